// Round 6
// baseline (579.848 us; speedup 1.0000x reference)
//
#include <hip/hip_runtime.h>
#include <hip/hip_bf16.h>

// Problem constants (B,N,D,H,E from reference; hd = D/H)
#define BB   2
#define NN   2048
#define DD   256
#define HH   8
#define HD   32
#define EE   65536
#define KTOP 1024   // N * (1 - 0.5)
#define NT   13     // float tensors to canonicalize
#define NSPLIT 4    // attention column splits

typedef __attribute__((ext_vector_type(8))) short bf16x8;
typedef __attribute__((ext_vector_type(4))) float f32x4;

__device__ __forceinline__ float bf2f(unsigned short u) {
    return __uint_as_float(((unsigned)u) << 16);
}
__device__ __forceinline__ unsigned short f2bf(float f) {
    __hip_bfloat16 h = __float2bfloat16(f);
    return *reinterpret_cast<unsigned short*>(&h);
}

// ---------------------------------------------------------------------------
// Dtype detector: read first 64K ushorts of x as bf16. fp32 data misread as
// bf16 has random exponents in the odd halves -> max blows past 1e10.
// flag: 1 = fp32, 0 = bf16.
// ---------------------------------------------------------------------------
__global__ __launch_bounds__(256) void k_detect(const void* __restrict__ x, int* __restrict__ flag)
{
    __shared__ float red[256];
    const unsigned short* u = (const unsigned short*)x;
    float mx = 0.f;
    for (int i = threadIdx.x; i < 65536; i += 256) {
        float v = fabsf(bf2f(u[i]));
        if (!(v <= 1e10f)) v = 1e30f;       // NaN / inf / huge -> big
        mx = fmaxf(mx, v);
    }
    red[threadIdx.x] = mx;
    __syncthreads();
    for (int s = 128; s > 0; s >>= 1) {
        if (threadIdx.x < s) red[threadIdx.x] = fmaxf(red[threadIdx.x], red[threadIdx.x + s]);
        __syncthreads();
    }
    if (threadIdx.x == 0) *flag = (red[0] > 1e10f) ? 1 : 0;
}

// ---------------------------------------------------------------------------
// Canonicalize float tensors to fp32 (+ optional bf16 copy) in workspace.
// ---------------------------------------------------------------------------
struct ConvArgs {
    const void*     src[NT];
    float*          dst[NT];
    unsigned short* dstB[NT];   // nullable: also emit bf16
    int             n[NT];
};

__global__ __launch_bounds__(256) void k_convert(ConvArgs a, const int* __restrict__ flag)
{
    int t = blockIdx.y;
    int n = a.n[t];
    int fp = *flag;
    const float* sf = (const float*)a.src[t];
    const unsigned short* sb = (const unsigned short*)a.src[t];
    float* d = a.dst[t];
    unsigned short* db = a.dstB[t];
    for (int i = blockIdx.x * 256 + threadIdx.x; i < n; i += gridDim.x * 256) {
        float v = fp ? sf[i] : bf2f(sb[i]);
        d[i] = v;
        if (db) db[i] = f2bf(v);
    }
}

// ---------------------------------------------------------------------------
// topo[b,n] = g2 @ relu(g1 @ x[b,n] + g1_b) + g2_b      (hidden = 128)
// Pure fp32 (top-k rank stability), coalesced tiled structure.
// ---------------------------------------------------------------------------
__global__ __launch_bounds__(256) void k_topo(
    const float* __restrict__ x,
    const float* __restrict__ g1w, const float* __restrict__ g1b,
    const float* __restrict__ g2w, const float* __restrict__ g2b,
    float* __restrict__ topo)
{
    __shared__ float xs[16][DD];        // 16 KB
    __shared__ float wt[16][129];       // staged g1w K-slice
    __shared__ float red[16][132];      // relu(h)*g2w contributions
    int t = threadIdx.x;
    int c  = t & 127;                   // hidden unit
    int rg = t >> 7;                    // 0/1 -> rows rg*8..+8
    int row0 = blockIdx.x * 16;

    const float4* X4 = reinterpret_cast<const float4*>(x + (size_t)row0 * DD);
    for (int i = t; i < 16 * 64; i += 256) {
        int r = i >> 6, k4 = i & 63;
        *reinterpret_cast<float4*>(&xs[r][k4 * 4]) = X4[(size_t)r * 64 + k4];
    }
    float acc[8];
#pragma unroll
    for (int r = 0; r < 8; ++r) acc[r] = 0.f;

    for (int kt = 0; kt < DD; kt += 16) {
        __syncthreads();
        for (int i = t; i < 128 * 16; i += 256) {
            int nn = i >> 4, kk = i & 15;
            wt[kk][nn] = g1w[(size_t)nn * DD + kt + kk];
        }
        __syncthreads();
        float wv[16];
#pragma unroll
        for (int kk = 0; kk < 16; ++kk) wv[kk] = wt[kk][c];
#pragma unroll
        for (int r = 0; r < 8; ++r) {
            const float* xr = &xs[rg * 8 + r][kt];
            float4 x0 = *reinterpret_cast<const float4*>(xr);
            float4 x1 = *reinterpret_cast<const float4*>(xr + 4);
            float4 x2 = *reinterpret_cast<const float4*>(xr + 8);
            float4 x3 = *reinterpret_cast<const float4*>(xr + 12);
            acc[r] += x0.x*wv[0] + x0.y*wv[1] + x0.z*wv[2] + x0.w*wv[3]
                    + x1.x*wv[4] + x1.y*wv[5] + x1.z*wv[6] + x1.w*wv[7]
                    + x2.x*wv[8] + x2.y*wv[9] + x2.z*wv[10] + x2.w*wv[11]
                    + x3.x*wv[12] + x3.y*wv[13] + x3.z*wv[14] + x3.w*wv[15];
        }
    }
    float gb = g1b[c], gw = g2w[c];
#pragma unroll
    for (int r = 0; r < 8; ++r)
        red[rg * 8 + r][c] = fmaxf(acc[r] + gb, 0.f) * gw;
    __syncthreads();
    int rr = t >> 4, ii = t & 15;       // 16 rows x 16 lanes
    float p = 0.f;
#pragma unroll
    for (int j = 0; j < 8; ++j) p += red[rr][ii * 8 + j];
#pragma unroll
    for (int o = 1; o < 16; o <<= 1) p += __shfl_xor(p, o, 64);
    if (ii == 0) topo[row0 + rr] = p + g2b[0];
}

// ---------------------------------------------------------------------------
// Stable top-k -> column bit mask (jax.lax.top_k stable-tie semantics).
// ---------------------------------------------------------------------------
__global__ __launch_bounds__(256) void k_rank(
    const float* __restrict__ topo, unsigned* __restrict__ colbits)
{
    int b = blockIdx.y;
    int m = blockIdx.x * 256 + threadIdx.x;
    __shared__ float tl[NN];
    for (int i = threadIdx.x; i < NN; i += 256) tl[i] = topo[b * NN + i];
    __syncthreads();
    float v = tl[m];
    int rank = 0;
    for (int j = 0; j < NN; ++j) {
        float vj = tl[j];
        rank += (vj > v) || (vj == v && j < m);
    }
    if (rank < KTOP) atomicOr(&colbits[b * 64 + (m >> 5)], 1u << (m & 31));
}

// ---------------------------------------------------------------------------
// Edge bitmask: edgebits[n][m/32] |= bit(m)
// ---------------------------------------------------------------------------
__global__ __launch_bounds__(256) void k_edges(
    const int* __restrict__ ei, unsigned* __restrict__ edgebits)
{
    int e = blockIdx.x * 256 + threadIdx.x;
    if (e >= EE) return;
    int r = ei[e];
    int c = ei[EE + e];
    atomicOr(&edgebits[r * 64 + (c >> 5)], 1u << (c & 31));
}

// ---------------------------------------------------------------------------
// sparse_mask output [B,H,N,N]: value = edge|col bit. Store dtype per flag.
// ---------------------------------------------------------------------------
__global__ __launch_bounds__(256) void k_maskout(
    const unsigned* __restrict__ edgebits, const unsigned* __restrict__ colbits,
    void* __restrict__ dout, const int* __restrict__ flag)
{
    int row = blockIdx.x;                 // b*N + n
    int b = row / NN, n = row % NN;
    int t = threadIdx.x;                  // covers cols t*8 .. t*8+7
    unsigned w = edgebits[n * 64 + (t >> 2)] | colbits[b * 64 + (t >> 2)];
    unsigned bits = (w >> ((t & 3) * 8)) & 0xFFu;
    if (*flag) {
        float v[8];
#pragma unroll
        for (int i = 0; i < 8; ++i) v[i] = ((bits >> i) & 1) ? 1.f : 0.f;
        float* base = (float*)dout + (size_t)BB * NN * DD;
#pragma unroll
        for (int h = 0; h < HH; ++h) {
            size_t idx = ((((size_t)(b * HH + h)) * NN + n) * NN) + (size_t)t * 8;
            *reinterpret_cast<float4*>(base + idx)     = make_float4(v[0], v[1], v[2], v[3]);
            *reinterpret_cast<float4*>(base + idx + 4) = make_float4(v[4], v[5], v[6], v[7]);
        }
    } else {
        unsigned v[8];
#pragma unroll
        for (int i = 0; i < 8; ++i) v[i] = ((bits >> i) & 1) ? 0x3F80u : 0u;
        uint4 o4;
        o4.x = v[0] | (v[1] << 16);
        o4.y = v[2] | (v[3] << 16);
        o4.z = v[4] | (v[5] << 16);
        o4.w = v[6] | (v[7] << 16);
        unsigned short* base = (unsigned short*)dout + (size_t)BB * NN * DD;
#pragma unroll
        for (int h = 0; h < HH; ++h) {
            size_t idx = ((((size_t)(b * HH + h)) * NN + n) * NN) + (size_t)t * 8;
            *reinterpret_cast<uint4*>(base + idx) = o4;
        }
    }
}

// ---------------------------------------------------------------------------
// Fused Q/K/V projection (one kernel, A-fragments loaded once).
// C[row,col] = X[row,:].W[col,:] + bias[col], K=256.
// Q,K -> bf16 head layout [b][h][n][j] (Q pre-scaled by 1/sqrt(hd));
// V -> bf16 transposed head layout [b][h][j][n].
// Grid (4096/64, 256/64); block = 4 waves.
// ---------------------------------------------------------------------------
__global__ __launch_bounds__(256) void k_proj3(
    const unsigned short* __restrict__ Xb,
    const unsigned short* __restrict__ Wq, const unsigned short* __restrict__ Wk,
    const unsigned short* __restrict__ Wv,
    const float* __restrict__ bq, const float* __restrict__ bk, const float* __restrict__ bv,
    unsigned short* __restrict__ Qo, unsigned short* __restrict__ Ko,
    unsigned short* __restrict__ Vo, float qscale)
{
    int t = threadIdx.x;
    int w = t >> 6, lane = t & 63, q4 = lane >> 4, l16 = lane & 15;
    int m0 = blockIdx.x * 64 + w * 16;
    int nb = blockIdx.y * 64;

    f32x4 aq[4] = {}, ak[4] = {}, av[4] = {};
#pragma unroll
    for (int ks = 0; ks < 8; ++ks) {
        bf16x8 a = *reinterpret_cast<const bf16x8*>(Xb + (size_t)(m0 + l16) * DD + ks * 32 + q4 * 8);
#pragma unroll
        for (int n = 0; n < 4; ++n) {
            size_t wo = (size_t)(nb + n * 16 + l16) * DD + ks * 32 + q4 * 8;
            bf16x8 b0 = *reinterpret_cast<const bf16x8*>(Wq + wo);
            bf16x8 b1 = *reinterpret_cast<const bf16x8*>(Wk + wo);
            bf16x8 b2 = *reinterpret_cast<const bf16x8*>(Wv + wo);
            aq[n] = __builtin_amdgcn_mfma_f32_16x16x32_bf16(a, b0, aq[n], 0, 0, 0);
            ak[n] = __builtin_amdgcn_mfma_f32_16x16x32_bf16(a, b1, ak[n], 0, 0, 0);
            av[n] = __builtin_amdgcn_mfma_f32_16x16x32_bf16(a, b2, av[n], 0, 0, 0);
        }
    }

#pragma unroll
    for (int n = 0; n < 4; ++n) {
        int col = nb + n * 16 + l16;
        int h = col >> 5, j = col & (HD - 1);
        float bvq = bq[col], bvk = bk[col], bvv = bv[col];
#pragma unroll
        for (int i = 0; i < 4; ++i) {
            int row = m0 + q4 * 4 + i;
            int b = row >> 11, n2 = row & (NN - 1);
            size_t ho = (((size_t)(b * HH + h)) * NN + n2) * HD + j;
            Qo[ho] = f2bf((aq[n][i] + bvq) * qscale);
            Ko[ho] = f2bf(ak[n][i] + bvk);
            Vo[(((size_t)(b * HH + h)) * HD + j) * NN + n2] = f2bf(av[n][i] + bvv);
        }
    }
}

// ---------------------------------------------------------------------------
// O-projection GEMM (MFMA), row-major store to d_out (dtype per flag).
// ---------------------------------------------------------------------------
__global__ __launch_bounds__(256) void k_projO(
    const unsigned short* __restrict__ Xb, const unsigned short* __restrict__ Wb,
    const float* __restrict__ bias, void* __restrict__ dout, const int* __restrict__ flag)
{
    int t = threadIdx.x;
    int w = t >> 6, lane = t & 63, q4 = lane >> 4, l16 = lane & 15;
    int m0 = blockIdx.x * 64 + w * 16;
    int nb = blockIdx.y * 64;

    f32x4 acc[4] = {};
#pragma unroll
    for (int ks = 0; ks < 8; ++ks) {
        bf16x8 a = *reinterpret_cast<const bf16x8*>(Xb + (size_t)(m0 + l16) * DD + ks * 32 + q4 * 8);
#pragma unroll
        for (int n = 0; n < 4; ++n) {
            bf16x8 bf = *reinterpret_cast<const bf16x8*>(Wb + (size_t)(nb + n * 16 + l16) * DD + ks * 32 + q4 * 8);
            acc[n] = __builtin_amdgcn_mfma_f32_16x16x32_bf16(a, bf, acc[n], 0, 0, 0);
        }
    }
    int fp = *flag;
#pragma unroll
    for (int n = 0; n < 4; ++n) {
        int col = nb + n * 16 + l16;
        float bv = bias[col];
#pragma unroll
        for (int i = 0; i < 4; ++i) {
            int row = m0 + q4 * 4 + i;
            float v = acc[n][i] + bv;
            if (fp) ((float*)dout)[(size_t)row * DD + col] = v;
            else ((unsigned short*)dout)[(size_t)row * DD + col] = f2bf(v);
        }
    }
}

// ---------------------------------------------------------------------------
// Fused masked attention, MFMA, split-K over columns (NSPLIT partials).
// No max-shift -> partials purely additive. K rows loaded as even/odd pairs
// (n0+2*l16, n0+2*l16+1) so each lane's two P values are column-adjacent ->
// single packed u32 LDS store. No asm barriers: compiler handles the P LDS
// RAW (same-wave DS ordering) and is free to software-pipeline K/V loads.
// ---------------------------------------------------------------------------
__global__ __launch_bounds__(256) void k_attn(
    const unsigned short* __restrict__ Qbf, const unsigned short* __restrict__ Kbf,
    const unsigned short* __restrict__ Vt,
    const unsigned* __restrict__ edgebits, const unsigned* __restrict__ colbits,
    float* __restrict__ Opart, float* __restrict__ Zpart, float* __restrict__ Spart)
{
    int blk   = blockIdx.x;
    int split = blk & (NSPLIT - 1);
    int rt    = blk >> 2;           // 64-row tile 0..31
    int h  = blockIdx.y;
    int b  = blockIdx.z;
    int t  = threadIdx.x;
    int w    = t >> 6;              // wave 0..3
    int lane = t & 63;
    int q4   = lane >> 4;           // quad 0..3
    int l16  = lane & 15;

    __shared__ unsigned mw[64][17];            // this split's mask words
    __shared__ short Pl[4][2][16 * 40];        // [wave][buf][row*40 + col]

    const int r0 = rt * 64;
    const int c0 = split * 16;                 // first chunk index
    for (int i = t; i < 64 * 16; i += 256) {
        int r = i >> 4, wd = i & 15;
        mw[r][wd] = edgebits[(r0 + r) * 64 + c0 + wd] | colbits[b * 64 + c0 + wd];
    }
    __syncthreads();

    const unsigned short* Qp = Qbf + ((size_t)(b * HH + h)) * NN * HD;
    const unsigned short* Kp = Kbf + ((size_t)(b * HH + h)) * NN * HD;
    const unsigned short* Vp = Vt  + ((size_t)(b * HH + h)) * HD * NN;

    bf16x8 afrag = *reinterpret_cast<const bf16x8*>(Qp + (size_t)(r0 + w * 16 + l16) * HD + q4 * 8);

    f32x4 O0 = {0.f, 0.f, 0.f, 0.f}, O1 = {0.f, 0.f, 0.f, 0.f};
    float Zp[4] = {0.f, 0.f, 0.f, 0.f}, Sp[4] = {0.f, 0.f, 0.f, 0.f};

    for (int chl = 0; chl < 16; ++chl) {
        int n0 = (c0 + chl) * 32;
        // even/odd K rows: s0 -> cols 2*l16, s1 -> cols 2*l16+1
        bf16x8 kb0 = *reinterpret_cast<const bf16x8*>(Kp + (size_t)(n0 + 2 * l16) * HD + q4 * 8);
        bf16x8 kb1 = *reinterpret_cast<const bf16x8*>(Kp + (size_t)(n0 + 2 * l16 + 1) * HD + q4 * 8);
        f32x4 s0 = __builtin_amdgcn_mfma_f32_16x16x32_bf16(afrag, kb0, (f32x4){0.f,0.f,0.f,0.f}, 0, 0, 0);
        f32x4 s1 = __builtin_amdgcn_mfma_f32_16x16x32_bf16(afrag, kb1, (f32x4){0.f,0.f,0.f,0.f}, 0, 0, 0);

        unsigned* P32 = reinterpret_cast<unsigned*>(&Pl[w][chl & 1][0]);   // row stride 20 u32
#pragma unroll
        for (int i = 0; i < 4; ++i) {
            int rl = w * 16 + q4 * 4 + i;          // block-local row
            unsigned wdv = mw[rl][chl];
            float e0 = __expf(s0[i]);
            float e1 = __expf(s1[i]);
            float m0 = ((wdv >> (2 * l16)) & 1u) ? e0 : 0.f;
            float m1 = ((wdv >> (2 * l16 + 1)) & 1u) ? e1 : 0.f;
            Zp[i] += e0 + e1;
            Sp[i] += m0 + m1;
            P32[(q4 * 4 + i) * 20 + l16] = (unsigned)f2bf(m0) | ((unsigned)f2bf(m1) << 16);
        }
        bf16x8 pfrag = *reinterpret_cast<const bf16x8*>(&Pl[w][chl & 1][l16 * 40 + q4 * 8]);
        bf16x8 vb0 = *reinterpret_cast<const bf16x8*>(Vp + (size_t)l16 * NN + n0 + q4 * 8);
        bf16x8 vb1 = *reinterpret_cast<const bf16x8*>(Vp + (size_t)(16 + l16) * NN + n0 + q4 * 8);
        O0 = __builtin_amdgcn_mfma_f32_16x16x32_bf16(pfrag, vb0, O0, 0, 0, 0);
        O1 = __builtin_amdgcn_mfma_f32_16x16x32_bf16(pfrag, vb1, O1, 0, 0, 0);
    }

#pragma unroll
    for (int o = 1; o < 16; o <<= 1) {
#pragma unroll
        for (int i = 0; i < 4; ++i) {
            Zp[i] += __shfl_xor(Zp[i], o, 64);
            Sp[i] += __shfl_xor(Sp[i], o, 64);
        }
    }
#pragma unroll
    for (int i = 0; i < 4; ++i) {
        int n = r0 + w * 16 + q4 * 4 + i;
        float* op = Opart + (size_t)split * BB * NN * DD + ((size_t)(b * NN + n)) * DD + h * HD;
        op[l16]      = O0[i];
        op[16 + l16] = O1[i];
        if (l16 == 0) {
            size_t zi = (((size_t)(split * BB + b)) * HH + h) * NN + n;
            Zpart[zi] = Zp[i];
            Spart[zi] = Sp[i];
        }
    }
}

// ---------------------------------------------------------------------------
// Combine split-K partials, normalize, emit bf16 AO. One block per (b,n).
// ---------------------------------------------------------------------------
__global__ __launch_bounds__(256) void k_comb(
    const float* __restrict__ Opart, const float* __restrict__ Zpart,
    const float* __restrict__ Spart, unsigned short* __restrict__ AOb)
{
    int row = blockIdx.x;       // b*N + n
    int t = threadIdx.x;        // d in 0..255
    int b = row >> 11, n = row & (NN - 1);
    int h = t >> 5;
    float Z = 0.f, S = 0.f, O = 0.f;
#pragma unroll
    for (int s = 0; s < NSPLIT; ++s) {
        size_t zi = (((size_t)(s * BB + b)) * HH + h) * NN + n;
        Z += Zpart[zi];
        S += Spart[zi];
        O += Opart[(size_t)s * BB * NN * DD + (size_t)row * DD + t];
    }
    AOb[(size_t)row * DD + t] = f2bf(O / (S + 1e-8f * Z));
}

// ---------------------------------------------------------------------------
extern "C" void kernel_launch(void* const* d_in, const int* in_sizes, int n_in,
                              void* d_out, int out_size, void* d_ws, size_t ws_size,
                              hipStream_t stream)
{
    const void* x   = d_in[0];
    const int*  ei  = (const int*)d_in[1];

    // workspace layout (bytes)
    char* ws = (char*)d_ws;
    constexpr size_t OFF_FLAG = 0;
    constexpr size_t OFF_EB   = 256;
    constexpr size_t OFF_CB   = OFF_EB  + (size_t)NN * 64 * 4;
    constexpr size_t OFF_TOPO = OFF_CB  + (size_t)BB * 64 * 4;
    constexpr size_t OFF_XF   = OFF_TOPO + (size_t)BB * NN * 4;
    constexpr size_t OFF_QW   = OFF_XF  + (size_t)BB * NN * DD * 4;
    constexpr size_t OFF_KW   = OFF_QW  + (size_t)DD * DD * 4;
    constexpr size_t OFF_VW   = OFF_KW  + (size_t)DD * DD * 4;
    constexpr size_t OFF_OW   = OFF_VW  + (size_t)DD * DD * 4;
    constexpr size_t OFF_QB   = OFF_OW  + (size_t)DD * DD * 4;
    constexpr size_t OFF_KB   = OFF_QB  + (size_t)DD * 4;
    constexpr size_t OFF_VB   = OFF_KB  + (size_t)DD * 4;
    constexpr size_t OFF_OB   = OFF_VB  + (size_t)DD * 4;
    constexpr size_t OFF_G1W  = OFF_OB  + (size_t)DD * 4;
    constexpr size_t OFF_G1B  = OFF_G1W + (size_t)(DD / 2) * DD * 4;
    constexpr size_t OFF_G2W  = OFF_G1B + (size_t)(DD / 2) * 4;
    constexpr size_t OFF_G2B  = OFF_G2W + (size_t)(DD / 2) * 4;
    constexpr size_t OFF_Q    = OFF_G2B + 256;                        // bf16 head layout
    constexpr size_t OFF_K    = OFF_Q   + (size_t)BB * NN * DD * 2;
    constexpr size_t OFF_VT   = OFF_K   + (size_t)BB * NN * DD * 2;   // bf16 transposed
    constexpr size_t OFF_AOB  = OFF_VT  + (size_t)BB * NN * DD * 2;   // bf16 attn out
    constexpr size_t OFF_XB   = OFF_AOB + (size_t)BB * NN * DD * 2;   // bf16 x
    constexpr size_t OFF_QWB  = OFF_XB  + (size_t)BB * NN * DD * 2;   // bf16 weights
    constexpr size_t OFF_KWB  = OFF_QWB + (size_t)DD * DD * 2;
    constexpr size_t OFF_VWB  = OFF_KWB + (size_t)DD * DD * 2;
    constexpr size_t OFF_OWB  = OFF_VWB + (size_t)DD * DD * 2;
    constexpr size_t OFF_OP   = OFF_OWB + (size_t)DD * DD * 2;        // split-K partials
    constexpr size_t OFF_ZP   = OFF_OP  + (size_t)NSPLIT * BB * NN * DD * 4;
    constexpr size_t OFF_SP   = OFF_ZP  + (size_t)NSPLIT * BB * HH * NN * 4;

    int*      flag     = (int*)(ws + OFF_FLAG);
    unsigned* edgebits = (unsigned*)(ws + OFF_EB);
    unsigned* colbits  = (unsigned*)(ws + OFF_CB);
    float*    topo     = (float*)(ws + OFF_TOPO);
    float*    xF       = (float*)(ws + OFF_XF);
    float*    qwF      = (float*)(ws + OFF_QW);
    float*    kwF      = (float*)(ws + OFF_KW);
    float*    vwF      = (float*)(ws + OFF_VW);
    float*    owF      = (float*)(ws + OFF_OW);
    float*    qbF      = (float*)(ws + OFF_QB);
    float*    kbF      = (float*)(ws + OFF_KB);
    float*    vbF      = (float*)(ws + OFF_VB);
    float*    obF      = (float*)(ws + OFF_OB);
    float*    g1wF     = (float*)(ws + OFF_G1W);
    float*    g1bF     = (float*)(ws + OFF_G1B);
    float*    g2wF     = (float*)(ws + OFF_G2W);
    float*    g2bF     = (float*)(ws + OFF_G2B);
    unsigned short* Qbf = (unsigned short*)(ws + OFF_Q);
    unsigned short* Kbf = (unsigned short*)(ws + OFF_K);
    unsigned short* Vtb = (unsigned short*)(ws + OFF_VT);
    unsigned short* AOb = (unsigned short*)(ws + OFF_AOB);
    unsigned short* Xbf = (unsigned short*)(ws + OFF_XB);
    unsigned short* qwB = (unsigned short*)(ws + OFF_QWB);
    unsigned short* kwB = (unsigned short*)(ws + OFF_KWB);
    unsigned short* vwB = (unsigned short*)(ws + OFF_VWB);
    unsigned short* owB = (unsigned short*)(ws + OFF_OWB);
    float*    Opart    = (float*)(ws + OFF_OP);
    float*    Zpart    = (float*)(ws + OFF_ZP);
    float*    Spart    = (float*)(ws + OFF_SP);

    // zero flag + edge/col bitmasks
    hipMemsetAsync(d_ws, 0, OFF_TOPO, stream);

    k_detect<<<dim3(1), dim3(256), 0, stream>>>(x, flag);

    ConvArgs ca;
    const int din_idx[NT] = {0, 2, 4, 6, 8, 3, 5, 7, 9, 10, 11, 12, 13};
    float* dsts[NT] = {xF, qwF, kwF, vwF, owF, qbF, kbF, vbF, obF, g1wF, g1bF, g2wF, g2bF};
    unsigned short* dstsB[NT] = {Xbf, qwB, kwB, vwB, owB,
                                 nullptr, nullptr, nullptr, nullptr,
                                 nullptr, nullptr, nullptr, nullptr};
    for (int i = 0; i < NT; ++i) {
        ca.src[i]  = d_in[din_idx[i]];
        ca.dst[i]  = dsts[i];
        ca.dstB[i] = dstsB[i];
        ca.n[i]    = in_sizes[din_idx[i]];
    }
    k_convert<<<dim3(64, NT), dim3(256), 0, stream>>>(ca, flag);

    k_topo<<<dim3(BB * NN / 16), dim3(256), 0, stream>>>(xF, g1wF, g1bF, g2wF, g2bF, topo);
    k_rank<<<dim3(NN / 256, BB), dim3(256), 0, stream>>>(topo, colbits);
    k_edges<<<dim3(EE / 256), dim3(256), 0, stream>>>(ei, edgebits);
    k_maskout<<<dim3(BB * NN), dim3(256), 0, stream>>>(edgebits, colbits, d_out, flag);

    const float qscale = 0.17677669529663687f;   // 1/sqrt(32)
    k_proj3<<<dim3(BB * NN / 64, DD / 64), dim3(256), 0, stream>>>(
        Xbf, qwB, kwB, vwB, qbF, kbF, vbF, Qbf, Kbf, Vtb, qscale);

    k_attn<<<dim3((NN / 64) * NSPLIT, HH, BB), dim3(256), 0, stream>>>(
        Qbf, Kbf, Vtb, edgebits, colbits, Opart, Zpart, Spart);
    k_comb<<<dim3(BB * NN), dim3(256), 0, stream>>>(Opart, Zpart, Spart, AOb);

    k_projO<<<dim3(BB * NN / 64, DD / 64), dim3(256), 0, stream>>>(AOb, owB, obF, d_out, flag);
}

// Round 7
// 512.587 us; speedup vs baseline: 1.1312x; 1.1312x over previous
//
#include <hip/hip_runtime.h>
#include <hip/hip_bf16.h>

// Problem constants (B,N,D,H,E from reference; hd = D/H)
#define BB   2
#define NN   2048
#define DD   256
#define HH   8
#define HD   32
#define EE   65536
#define KTOP 1024   // N * (1 - 0.5)
#define NT   13     // float tensors to canonicalize
#define NSPLIT 2    // attention column splits

typedef __attribute__((ext_vector_type(8))) short bf16x8;
typedef __attribute__((ext_vector_type(4))) float f32x4;

__device__ __forceinline__ float bf2f(unsigned short u) {
    return __uint_as_float(((unsigned)u) << 16);
}
__device__ __forceinline__ unsigned short f2bf(float f) {
    __hip_bfloat16 h = __float2bfloat16(f);
    return *reinterpret_cast<unsigned short*>(&h);
}

// ---------------------------------------------------------------------------
// Dtype detector (vectorized): read first 128KB of x as bf16 halves. fp32
// misread as bf16 -> random exponents -> max >> 1e10. flag: 1=fp32, 0=bf16.
// ---------------------------------------------------------------------------
__global__ __launch_bounds__(256) void k_detect(const void* __restrict__ x, int* __restrict__ flag)
{
    __shared__ float red[256];
    const uint4* u = (const uint4*)x;       // 8 ushorts per load
    float mx = 0.f;
    for (int i = threadIdx.x; i < 8192; i += 256) {
        uint4 p = u[i];
        unsigned wds[4] = {p.x, p.y, p.z, p.w};
#pragma unroll
        for (int k = 0; k < 4; ++k) {
            float a = fabsf(bf2f((unsigned short)(wds[k] & 0xFFFF)));
            float b = fabsf(bf2f((unsigned short)(wds[k] >> 16)));
            if (!(a <= 1e10f)) a = 1e30f;
            if (!(b <= 1e10f)) b = 1e30f;
            mx = fmaxf(mx, fmaxf(a, b));
        }
    }
    red[threadIdx.x] = mx;
    __syncthreads();
    for (int s = 128; s > 0; s >>= 1) {
        if (threadIdx.x < s) red[threadIdx.x] = fmaxf(red[threadIdx.x], red[threadIdx.x + s]);
        __syncthreads();
    }
    if (threadIdx.x == 0) *flag = (red[0] > 1e10f) ? 1 : 0;
}

// ---------------------------------------------------------------------------
// Canonicalize float tensors to fp32 (+ optional bf16 copy), vectorized.
// ---------------------------------------------------------------------------
struct ConvArgs {
    const void*     src[NT];
    float*          dst[NT];
    unsigned short* dstB[NT];   // nullable: also emit bf16
    int             n[NT];
};

__global__ __launch_bounds__(256) void k_convert(ConvArgs a, const int* __restrict__ flag)
{
    int ts = blockIdx.y;
    int n = a.n[ts];
    int fp = *flag;
    const float* sf = (const float*)a.src[ts];
    const unsigned short* sb = (const unsigned short*)a.src[ts];
    float* d = a.dst[ts];
    unsigned short* db = a.dstB[ts];
    int n4 = n >> 2;
    int gtid = blockIdx.x * 256 + threadIdx.x;
    int gstr = gridDim.x * 256;
    for (int i = gtid; i < n4; i += gstr) {
        float4 v;
        if (fp) v = ((const float4*)sf)[i];
        else {
            ushort4 u = ((const ushort4*)sb)[i];
            v = make_float4(bf2f(u.x), bf2f(u.y), bf2f(u.z), bf2f(u.w));
        }
        ((float4*)d)[i] = v;
        if (db) {
            ushort4 o; o.x = f2bf(v.x); o.y = f2bf(v.y); o.z = f2bf(v.z); o.w = f2bf(v.w);
            ((ushort4*)db)[i] = o;
        }
    }
    for (int i = n4 * 4 + gtid; i < n; i += gstr) {
        float v = fp ? sf[i] : bf2f(sb[i]);
        d[i] = v;
        if (db) db[i] = f2bf(v);
    }
}

// ---------------------------------------------------------------------------
// topo[b,n] = g2 @ relu(g1 @ x[b,n] + g1_b) + g2_b      (hidden = 128)
// Pure fp32 (top-k rank stability), coalesced tiled structure.
// ---------------------------------------------------------------------------
__global__ __launch_bounds__(256) void k_topo(
    const float* __restrict__ x,
    const float* __restrict__ g1w, const float* __restrict__ g1b,
    const float* __restrict__ g2w, const float* __restrict__ g2b,
    float* __restrict__ topo)
{
    __shared__ float xs[16][DD];
    __shared__ float wt[16][129];
    __shared__ float red[16][132];
    int t = threadIdx.x;
    int c  = t & 127;
    int rg = t >> 7;
    int row0 = blockIdx.x * 16;

    const float4* X4 = reinterpret_cast<const float4*>(x + (size_t)row0 * DD);
    for (int i = t; i < 16 * 64; i += 256) {
        int r = i >> 6, k4 = i & 63;
        *reinterpret_cast<float4*>(&xs[r][k4 * 4]) = X4[(size_t)r * 64 + k4];
    }
    float acc[8];
#pragma unroll
    for (int r = 0; r < 8; ++r) acc[r] = 0.f;

    for (int kt = 0; kt < DD; kt += 16) {
        __syncthreads();
        for (int i = t; i < 128 * 16; i += 256) {
            int nn = i >> 4, kk = i & 15;
            wt[kk][nn] = g1w[(size_t)nn * DD + kt + kk];
        }
        __syncthreads();
        float wv[16];
#pragma unroll
        for (int kk = 0; kk < 16; ++kk) wv[kk] = wt[kk][c];
#pragma unroll
        for (int r = 0; r < 8; ++r) {
            const float* xr = &xs[rg * 8 + r][kt];
            float4 x0 = *reinterpret_cast<const float4*>(xr);
            float4 x1 = *reinterpret_cast<const float4*>(xr + 4);
            float4 x2 = *reinterpret_cast<const float4*>(xr + 8);
            float4 x3 = *reinterpret_cast<const float4*>(xr + 12);
            acc[r] += x0.x*wv[0] + x0.y*wv[1] + x0.z*wv[2] + x0.w*wv[3]
                    + x1.x*wv[4] + x1.y*wv[5] + x1.z*wv[6] + x1.w*wv[7]
                    + x2.x*wv[8] + x2.y*wv[9] + x2.z*wv[10] + x2.w*wv[11]
                    + x3.x*wv[12] + x3.y*wv[13] + x3.z*wv[14] + x3.w*wv[15];
        }
    }
    float gb = g1b[c], gw = g2w[c];
#pragma unroll
    for (int r = 0; r < 8; ++r)
        red[rg * 8 + r][c] = fmaxf(acc[r] + gb, 0.f) * gw;
    __syncthreads();
    int rr = t >> 4, ii = t & 15;
    float p = 0.f;
#pragma unroll
    for (int j = 0; j < 8; ++j) p += red[rr][ii * 8 + j];
#pragma unroll
    for (int o = 1; o < 16; o <<= 1) p += __shfl_xor(p, o, 64);
    if (ii == 0) topo[row0 + rr] = p + g2b[0];
}

// ---------------------------------------------------------------------------
// Stable top-k -> column bit mask (jax.lax.top_k stable-tie semantics).
// float4 LDS reads: 512 b128 iterations instead of 2048 serialized b32.
// ---------------------------------------------------------------------------
__global__ __launch_bounds__(256) void k_rank(
    const float* __restrict__ topo, unsigned* __restrict__ colbits)
{
    int b = blockIdx.y;
    int m = blockIdx.x * 256 + threadIdx.x;
    __shared__ float tl[NN];
    for (int i = threadIdx.x; i < NN / 4; i += 256)
        *reinterpret_cast<float4*>(&tl[i * 4]) =
            reinterpret_cast<const float4*>(topo + b * NN)[i];
    __syncthreads();
    float v = tl[m];
    int rank = 0;
    for (int j4 = 0; j4 < NN / 4; ++j4) {
        float4 q = *reinterpret_cast<const float4*>(&tl[j4 * 4]);
        int j = j4 * 4;
        rank += (q.x > v) || (q.x == v && (j + 0) < m);
        rank += (q.y > v) || (q.y == v && (j + 1) < m);
        rank += (q.z > v) || (q.z == v && (j + 2) < m);
        rank += (q.w > v) || (q.w == v && (j + 3) < m);
    }
    if (rank < KTOP) atomicOr(&colbits[b * 64 + (m >> 5)], 1u << (m & 31));
}

// ---------------------------------------------------------------------------
// Edge bitmask: edgebits[n][m/32] |= bit(m)
// ---------------------------------------------------------------------------
__global__ __launch_bounds__(256) void k_edges(
    const int* __restrict__ ei, unsigned* __restrict__ edgebits)
{
    int e = blockIdx.x * 256 + threadIdx.x;
    if (e >= EE) return;
    int r = ei[e];
    int c = ei[EE + e];
    atomicOr(&edgebits[r * 64 + (c >> 5)], 1u << (c & 31));
}

// ---------------------------------------------------------------------------
// sparse_mask output [B,H,N,N]: value = edge|col bit. Store dtype per flag.
// ---------------------------------------------------------------------------
__global__ __launch_bounds__(256) void k_maskout(
    const unsigned* __restrict__ edgebits, const unsigned* __restrict__ colbits,
    void* __restrict__ dout, const int* __restrict__ flag)
{
    int row = blockIdx.x;                 // b*N + n
    int b = row / NN, n = row % NN;
    int t = threadIdx.x;                  // covers cols t*8 .. t*8+7
    unsigned w = edgebits[n * 64 + (t >> 2)] | colbits[b * 64 + (t >> 2)];
    unsigned bits = (w >> ((t & 3) * 8)) & 0xFFu;
    if (*flag) {
        float v[8];
#pragma unroll
        for (int i = 0; i < 8; ++i) v[i] = ((bits >> i) & 1) ? 1.f : 0.f;
        float* base = (float*)dout + (size_t)BB * NN * DD;
#pragma unroll
        for (int h = 0; h < HH; ++h) {
            size_t idx = ((((size_t)(b * HH + h)) * NN + n) * NN) + (size_t)t * 8;
            *reinterpret_cast<float4*>(base + idx)     = make_float4(v[0], v[1], v[2], v[3]);
            *reinterpret_cast<float4*>(base + idx + 4) = make_float4(v[4], v[5], v[6], v[7]);
        }
    } else {
        unsigned v[8];
#pragma unroll
        for (int i = 0; i < 8; ++i) v[i] = ((bits >> i) & 1) ? 0x3F80u : 0u;
        uint4 o4;
        o4.x = v[0] | (v[1] << 16);
        o4.y = v[2] | (v[3] << 16);
        o4.z = v[4] | (v[5] << 16);
        o4.w = v[6] | (v[7] << 16);
        unsigned short* base = (unsigned short*)dout + (size_t)BB * NN * DD;
#pragma unroll
        for (int h = 0; h < HH; ++h) {
            size_t idx = ((((size_t)(b * HH + h)) * NN + n) * NN) + (size_t)t * 8;
            *reinterpret_cast<uint4*>(base + idx) = o4;
        }
    }
}

// ---------------------------------------------------------------------------
// Fused Q/K/V projection (one kernel, A-fragments loaded once).
// Q,K -> bf16 head layout [b][h][n][j] (Q pre-scaled); V -> [b][h][j][n].
// ---------------------------------------------------------------------------
__global__ __launch_bounds__(256) void k_proj3(
    const unsigned short* __restrict__ Xb,
    const unsigned short* __restrict__ Wq, const unsigned short* __restrict__ Wk,
    const unsigned short* __restrict__ Wv,
    const float* __restrict__ bq, const float* __restrict__ bk, const float* __restrict__ bv,
    unsigned short* __restrict__ Qo, unsigned short* __restrict__ Ko,
    unsigned short* __restrict__ Vo, float qscale)
{
    int t = threadIdx.x;
    int w = t >> 6, lane = t & 63, q4 = lane >> 4, l16 = lane & 15;
    int m0 = blockIdx.x * 64 + w * 16;
    int nb = blockIdx.y * 64;

    f32x4 aq[4] = {}, ak[4] = {}, av[4] = {};
#pragma unroll
    for (int ks = 0; ks < 8; ++ks) {
        bf16x8 a = *reinterpret_cast<const bf16x8*>(Xb + (size_t)(m0 + l16) * DD + ks * 32 + q4 * 8);
#pragma unroll
        for (int n = 0; n < 4; ++n) {
            size_t wo = (size_t)(nb + n * 16 + l16) * DD + ks * 32 + q4 * 8;
            bf16x8 b0 = *reinterpret_cast<const bf16x8*>(Wq + wo);
            bf16x8 b1 = *reinterpret_cast<const bf16x8*>(Wk + wo);
            bf16x8 b2 = *reinterpret_cast<const bf16x8*>(Wv + wo);
            aq[n] = __builtin_amdgcn_mfma_f32_16x16x32_bf16(a, b0, aq[n], 0, 0, 0);
            ak[n] = __builtin_amdgcn_mfma_f32_16x16x32_bf16(a, b1, ak[n], 0, 0, 0);
            av[n] = __builtin_amdgcn_mfma_f32_16x16x32_bf16(a, b2, av[n], 0, 0, 0);
        }
    }

#pragma unroll
    for (int n = 0; n < 4; ++n) {
        int col = nb + n * 16 + l16;
        int h = col >> 5, j = col & (HD - 1);
        float bvq = bq[col], bvk = bk[col], bvv = bv[col];
#pragma unroll
        for (int i = 0; i < 4; ++i) {
            int row = m0 + q4 * 4 + i;
            int b = row >> 11, n2 = row & (NN - 1);
            size_t ho = (((size_t)(b * HH + h)) * NN + n2) * HD + j;
            Qo[ho] = f2bf((aq[n][i] + bvq) * qscale);
            Ko[ho] = f2bf(ak[n][i] + bvk);
            Vo[(((size_t)(b * HH + h)) * HD + j) * NN + n2] = f2bf(av[n][i] + bvv);
        }
    }
}

// ---------------------------------------------------------------------------
// Fused masked attention, MFMA, split-K over columns (NSPLIT=2 partials).
// Explicit one-chunk prefetch rotation of K/V registers (forces software
// pipelining the compiler was not doing). RTZ bf16 pack for P (3 VALU).
// ---------------------------------------------------------------------------
__global__ __launch_bounds__(256) void k_attn(
    const unsigned short* __restrict__ Qbf, const unsigned short* __restrict__ Kbf,
    const unsigned short* __restrict__ Vt,
    const unsigned* __restrict__ edgebits, const unsigned* __restrict__ colbits,
    float* __restrict__ Opart, float* __restrict__ Zpart, float* __restrict__ Spart)
{
    int blk   = blockIdx.x;
    int split = blk & (NSPLIT - 1);
    int rt    = blk >> 1;           // 64-row tile 0..31
    int h  = blockIdx.y;
    int b  = blockIdx.z;
    int t  = threadIdx.x;
    int w    = t >> 6;              // wave 0..3
    int lane = t & 63;
    int q4   = lane >> 4;           // quad 0..3
    int l16  = lane & 15;

    __shared__ unsigned mw[64][33];            // this split's 32 mask words (+pad)
    __shared__ short Pl[4][2][16 * 40];        // [wave][buf][row*40 + col]

    const int r0 = rt * 64;
    const int c0 = split * 32;                 // first chunk index
    for (int i = t; i < 64 * 32; i += 256) {
        int r = i >> 5, wd = i & 31;
        mw[r][wd] = edgebits[(r0 + r) * 64 + c0 + wd] | colbits[b * 64 + c0 + wd];
    }
    __syncthreads();

    const unsigned short* Qp = Qbf + ((size_t)(b * HH + h)) * NN * HD;
    const unsigned short* Kp = Kbf + ((size_t)(b * HH + h)) * NN * HD;
    const unsigned short* Vp = Vt  + ((size_t)(b * HH + h)) * HD * NN;

    bf16x8 afrag = *reinterpret_cast<const bf16x8*>(Qp + (size_t)(r0 + w * 16 + l16) * HD + q4 * 8);

    f32x4 O0 = {0.f, 0.f, 0.f, 0.f}, O1 = {0.f, 0.f, 0.f, 0.f};
    float Zp[4] = {0.f, 0.f, 0.f, 0.f}, Sp[4] = {0.f, 0.f, 0.f, 0.f};

    // prefetch chunk 0
    bf16x8 kb0, kb1, vb0, vb1;
    {
        int n0 = c0 * 32;
        kb0 = *reinterpret_cast<const bf16x8*>(Kp + (size_t)(n0 + 2 * l16) * HD + q4 * 8);
        kb1 = *reinterpret_cast<const bf16x8*>(Kp + (size_t)(n0 + 2 * l16 + 1) * HD + q4 * 8);
        vb0 = *reinterpret_cast<const bf16x8*>(Vp + (size_t)l16 * NN + n0 + q4 * 8);
        vb1 = *reinterpret_cast<const bf16x8*>(Vp + (size_t)(16 + l16) * NN + n0 + q4 * 8);
    }

    for (int chl = 0; chl < 32; ++chl) {
        // issue next chunk's loads BEFORE consuming this chunk's registers
        int nxt = (chl + 1 < 32) ? chl + 1 : 31;
        int nn0 = (c0 + nxt) * 32;
        bf16x8 nk0 = *reinterpret_cast<const bf16x8*>(Kp + (size_t)(nn0 + 2 * l16) * HD + q4 * 8);
        bf16x8 nk1 = *reinterpret_cast<const bf16x8*>(Kp + (size_t)(nn0 + 2 * l16 + 1) * HD + q4 * 8);
        bf16x8 nv0 = *reinterpret_cast<const bf16x8*>(Vp + (size_t)l16 * NN + nn0 + q4 * 8);
        bf16x8 nv1 = *reinterpret_cast<const bf16x8*>(Vp + (size_t)(16 + l16) * NN + nn0 + q4 * 8);

        f32x4 s0 = __builtin_amdgcn_mfma_f32_16x16x32_bf16(afrag, kb0, (f32x4){0.f,0.f,0.f,0.f}, 0, 0, 0);
        f32x4 s1 = __builtin_amdgcn_mfma_f32_16x16x32_bf16(afrag, kb1, (f32x4){0.f,0.f,0.f,0.f}, 0, 0, 0);

        unsigned* P32 = reinterpret_cast<unsigned*>(&Pl[w][chl & 1][0]);   // row stride 20 u32
#pragma unroll
        for (int i = 0; i < 4; ++i) {
            int rl = w * 16 + q4 * 4 + i;          // block-local row
            unsigned wdv = mw[rl][chl];
            float e0 = __expf(s0[i]);
            float e1 = __expf(s1[i]);
            float m0 = ((wdv >> (2 * l16)) & 1u) ? e0 : 0.f;
            float m1 = ((wdv >> (2 * l16 + 1)) & 1u) ? e1 : 0.f;
            Zp[i] += e0 + e1;
            Sp[i] += m0 + m1;
            // RTZ bf16 pack (P enters numerator only; bias << threshold)
            P32[(q4 * 4 + i) * 20 + l16] =
                (__float_as_uint(m0) >> 16) | (__float_as_uint(m1) & 0xFFFF0000u);
        }
        bf16x8 pfrag = *reinterpret_cast<const bf16x8*>(&Pl[w][chl & 1][l16 * 40 + q4 * 8]);
        O0 = __builtin_amdgcn_mfma_f32_16x16x32_bf16(pfrag, vb0, O0, 0, 0, 0);
        O1 = __builtin_amdgcn_mfma_f32_16x16x32_bf16(pfrag, vb1, O1, 0, 0, 0);

        kb0 = nk0; kb1 = nk1; vb0 = nv0; vb1 = nv1;
    }

#pragma unroll
    for (int o = 1; o < 16; o <<= 1) {
#pragma unroll
        for (int i = 0; i < 4; ++i) {
            Zp[i] += __shfl_xor(Zp[i], o, 64);
            Sp[i] += __shfl_xor(Sp[i], o, 64);
        }
    }
#pragma unroll
    for (int i = 0; i < 4; ++i) {
        int n = r0 + w * 16 + q4 * 4 + i;
        float* op = Opart + (size_t)split * BB * NN * DD + ((size_t)(b * NN + n)) * DD + h * HD;
        op[l16]      = O0[i];
        op[16 + l16] = O1[i];
        if (l16 == 0) {
            size_t zi = (((size_t)(split * BB + b)) * HH + h) * NN + n;
            Zpart[zi] = Zp[i];
            Spart[zi] = Sp[i];
        }
    }
}

// ---------------------------------------------------------------------------
// O-projection GEMM (MFMA) with fused split-K combine + normalize:
// A[row][k] = (sum_s Opart[s][row][k]) / (S+1e-8 Z), head h = k/32.
// Row-major store to d_out (dtype per flag).
// ---------------------------------------------------------------------------
__global__ __launch_bounds__(256) void k_projO(
    const float* __restrict__ Opart, const float* __restrict__ Zpart,
    const float* __restrict__ Spart,
    const unsigned short* __restrict__ Wb, const float* __restrict__ bias,
    void* __restrict__ dout, const int* __restrict__ flag)
{
    int t = threadIdx.x;
    int w = t >> 6, lane = t & 63, q4 = lane >> 4, l16 = lane & 15;
    int m0 = blockIdx.x * 64 + w * 16;
    int nb = blockIdx.y * 64;
    int arow = m0 + l16;                     // A row this lane loads
    int ab = arow >> 11, an = arow & (NN - 1);

    f32x4 acc[4] = {};
#pragma unroll
    for (int ks = 0; ks < 8; ++ks) {        // head h = ks
        size_t zi0 = (((size_t)(0 * BB + ab)) * HH + ks) * NN + an;
        size_t zi1 = (((size_t)(1 * BB + ab)) * HH + ks) * NN + an;
        float Zt = Zpart[zi0] + Zpart[zi1];
        float St = Spart[zi0] + Spart[zi1];
        float inv = 1.f / (St + 1e-8f * Zt);
        const float* o0 = Opart + (size_t)arow * DD + ks * 32 + q4 * 8;
        const float* o1 = o0 + (size_t)BB * NN * DD;
        bf16x8 a;
#pragma unroll
        for (int j = 0; j < 8; ++j)
            a[j] = (short)f2bf((o0[j] + o1[j]) * inv);
#pragma unroll
        for (int n = 0; n < 4; ++n) {
            bf16x8 bf = *reinterpret_cast<const bf16x8*>(Wb + (size_t)(nb + n * 16 + l16) * DD + ks * 32 + q4 * 8);
            acc[n] = __builtin_amdgcn_mfma_f32_16x16x32_bf16(a, bf, acc[n], 0, 0, 0);
        }
    }
    int fp = *flag;
#pragma unroll
    for (int n = 0; n < 4; ++n) {
        int col = nb + n * 16 + l16;
        float bv = bias[col];
#pragma unroll
        for (int i = 0; i < 4; ++i) {
            int row = m0 + q4 * 4 + i;
            float v = acc[n][i] + bv;
            if (fp) ((float*)dout)[(size_t)row * DD + col] = v;
            else ((unsigned short*)dout)[(size_t)row * DD + col] = f2bf(v);
        }
    }
}

// ---------------------------------------------------------------------------
extern "C" void kernel_launch(void* const* d_in, const int* in_sizes, int n_in,
                              void* d_out, int out_size, void* d_ws, size_t ws_size,
                              hipStream_t stream)
{
    const void* x   = d_in[0];
    const int*  ei  = (const int*)d_in[1];

    // workspace layout (bytes)
    char* ws = (char*)d_ws;
    constexpr size_t OFF_FLAG = 0;
    constexpr size_t OFF_EB   = 256;
    constexpr size_t OFF_CB   = OFF_EB  + (size_t)NN * 64 * 4;
    constexpr size_t OFF_TOPO = OFF_CB  + (size_t)BB * 64 * 4;
    constexpr size_t OFF_XF   = OFF_TOPO + (size_t)BB * NN * 4;
    constexpr size_t OFF_QW   = OFF_XF  + (size_t)BB * NN * DD * 4;
    constexpr size_t OFF_KW   = OFF_QW  + (size_t)DD * DD * 4;
    constexpr size_t OFF_VW   = OFF_KW  + (size_t)DD * DD * 4;
    constexpr size_t OFF_OW   = OFF_VW  + (size_t)DD * DD * 4;
    constexpr size_t OFF_QB   = OFF_OW  + (size_t)DD * DD * 4;
    constexpr size_t OFF_KB   = OFF_QB  + (size_t)DD * 4;
    constexpr size_t OFF_VB   = OFF_KB  + (size_t)DD * 4;
    constexpr size_t OFF_OB   = OFF_VB  + (size_t)DD * 4;
    constexpr size_t OFF_G1W  = OFF_OB  + (size_t)DD * 4;
    constexpr size_t OFF_G1B  = OFF_G1W + (size_t)(DD / 2) * DD * 4;
    constexpr size_t OFF_G2W  = OFF_G1B + (size_t)(DD / 2) * 4;
    constexpr size_t OFF_G2B  = OFF_G2W + (size_t)(DD / 2) * 4;
    constexpr size_t OFF_Q    = OFF_G2B + 256;                        // bf16 head layout
    constexpr size_t OFF_K    = OFF_Q   + (size_t)BB * NN * DD * 2;
    constexpr size_t OFF_VT   = OFF_K   + (size_t)BB * NN * DD * 2;   // bf16 transposed
    constexpr size_t OFF_XB   = OFF_VT  + (size_t)BB * NN * DD * 2;   // bf16 x
    constexpr size_t OFF_QWB  = OFF_XB  + (size_t)BB * NN * DD * 2;   // bf16 weights
    constexpr size_t OFF_KWB  = OFF_QWB + (size_t)DD * DD * 2;
    constexpr size_t OFF_VWB  = OFF_KWB + (size_t)DD * DD * 2;
    constexpr size_t OFF_OWB  = OFF_VWB + (size_t)DD * DD * 2;
    constexpr size_t OFF_OP   = OFF_OWB + (size_t)DD * DD * 2;        // split-K partials
    constexpr size_t OFF_ZP   = OFF_OP  + (size_t)NSPLIT * BB * NN * DD * 4;
    constexpr size_t OFF_SP   = OFF_ZP  + (size_t)NSPLIT * BB * HH * NN * 4;

    int*      flag     = (int*)(ws + OFF_FLAG);
    unsigned* edgebits = (unsigned*)(ws + OFF_EB);
    unsigned* colbits  = (unsigned*)(ws + OFF_CB);
    float*    topo     = (float*)(ws + OFF_TOPO);
    float*    xF       = (float*)(ws + OFF_XF);
    float*    qwF      = (float*)(ws + OFF_QW);
    float*    kwF      = (float*)(ws + OFF_KW);
    float*    vwF      = (float*)(ws + OFF_VW);
    float*    owF      = (float*)(ws + OFF_OW);
    float*    qbF      = (float*)(ws + OFF_QB);
    float*    kbF      = (float*)(ws + OFF_KB);
    float*    vbF      = (float*)(ws + OFF_VB);
    float*    obF      = (float*)(ws + OFF_OB);
    float*    g1wF     = (float*)(ws + OFF_G1W);
    float*    g1bF     = (float*)(ws + OFF_G1B);
    float*    g2wF     = (float*)(ws + OFF_G2W);
    float*    g2bF     = (float*)(ws + OFF_G2B);
    unsigned short* Qbf = (unsigned short*)(ws + OFF_Q);
    unsigned short* Kbf = (unsigned short*)(ws + OFF_K);
    unsigned short* Vtb = (unsigned short*)(ws + OFF_VT);
    unsigned short* Xbf = (unsigned short*)(ws + OFF_XB);
    unsigned short* qwB = (unsigned short*)(ws + OFF_QWB);
    unsigned short* kwB = (unsigned short*)(ws + OFF_KWB);
    unsigned short* vwB = (unsigned short*)(ws + OFF_VWB);
    unsigned short* owB = (unsigned short*)(ws + OFF_OWB);
    float*    Opart    = (float*)(ws + OFF_OP);
    float*    Zpart    = (float*)(ws + OFF_ZP);
    float*    Spart    = (float*)(ws + OFF_SP);

    // zero flag + edge/col bitmasks
    hipMemsetAsync(d_ws, 0, OFF_TOPO, stream);

    k_detect<<<dim3(1), dim3(256), 0, stream>>>(x, flag);

    ConvArgs ca;
    const int din_idx[NT] = {0, 2, 4, 6, 8, 3, 5, 7, 9, 10, 11, 12, 13};
    float* dsts[NT] = {xF, qwF, kwF, vwF, owF, qbF, kbF, vbF, obF, g1wF, g1bF, g2wF, g2bF};
    unsigned short* dstsB[NT] = {Xbf, qwB, kwB, vwB, owB,
                                 nullptr, nullptr, nullptr, nullptr,
                                 nullptr, nullptr, nullptr, nullptr};
    for (int i = 0; i < NT; ++i) {
        ca.src[i]  = d_in[din_idx[i]];
        ca.dst[i]  = dsts[i];
        ca.dstB[i] = dstsB[i];
        ca.n[i]    = in_sizes[din_idx[i]];
    }
    k_convert<<<dim3(64, NT), dim3(256), 0, stream>>>(ca, flag);

    k_topo<<<dim3(BB * NN / 16), dim3(256), 0, stream>>>(xF, g1wF, g1bF, g2wF, g2bF, topo);
    k_rank<<<dim3(NN / 256, BB), dim3(256), 0, stream>>>(topo, colbits);
    k_edges<<<dim3(EE / 256), dim3(256), 0, stream>>>(ei, edgebits);
    k_maskout<<<dim3(BB * NN), dim3(256), 0, stream>>>(edgebits, colbits, d_out, flag);

    const float qscale = 0.17677669529663687f;   // 1/sqrt(32)
    k_proj3<<<dim3(BB * NN / 64, DD / 64), dim3(256), 0, stream>>>(
        Xbf, qwB, kwB, vwB, qbF, kbF, vbF, Qbf, Kbf, Vtb, qscale);

    k_attn<<<dim3((NN / 64) * NSPLIT, HH, BB), dim3(256), 0, stream>>>(
        Qbf, Kbf, Vtb, edgebits, colbits, Opart, Zpart, Spart);

    k_projO<<<dim3(BB * NN / 64, DD / 64), dim3(256), 0, stream>>>(
        Opart, Zpart, Spart, owB, obF, d_out, flag);
}

// Round 8
// 481.453 us; speedup vs baseline: 1.2044x; 1.0647x over previous
//
#include <hip/hip_runtime.h>
#include <hip/hip_bf16.h>

// Problem constants (B,N,D,H,E from reference; hd = D/H)
#define BB   2
#define NN   2048
#define DD   256
#define HH   8
#define HD   32
#define EE   65536
#define KTOP 1024   // N * (1 - 0.5)
#define NSPLIT 2    // attention column splits

typedef __attribute__((ext_vector_type(8))) short bf16x8;
typedef __attribute__((ext_vector_type(4))) float f32x4;

__device__ __forceinline__ float bf2f(unsigned short u) {
    return __uint_as_float(((unsigned)u) << 16);
}
__device__ __forceinline__ unsigned short f2bf(float f) {
    __hip_bfloat16 h = __float2bfloat16(f);
    return *reinterpret_cast<unsigned short*>(&h);
}
// raw scalar load with dtype branch
__device__ __forceinline__ float loadf(const void* p, int i, int fp) {
    return fp ? ((const float*)p)[i] : bf2f(((const unsigned short*)p)[i]);
}

// ---------------------------------------------------------------------------
// Inline dtype detection: wave ballot over first 64 u32 words of x.
// fp32 misread as bf16 -> low halves have random exponents -> |v| > 1e10
// w.p. ~0.37 per word; P(miss over 64 words) ~ 1e-13. Wave-uniform result,
// identical for every wave/block/kernel (same 64 words). 1 = fp32, 0 = bf16.
// ---------------------------------------------------------------------------
__device__ __forceinline__ int derive_fp32(const void* x) {
    unsigned wv = ((const unsigned*)x)[threadIdx.x & 63];
    float a = fabsf(bf2f((unsigned short)(wv & 0xFFFFu)));
    float b = fabsf(bf2f((unsigned short)(wv >> 16)));
    bool bad = !(a <= 1e10f && b <= 1e10f);     // catches NaN/inf/huge
    return __ballot(bad) != 0ULL;
}

// ---------------------------------------------------------------------------
// FRONT layer (one dispatch): blocks
//   [0,64)    x -> Xbf (bf16)
//   [64,80)   qw/kw/vw/ow -> bf16
//   [80,336)  topo MLP (fp32 math from raw inputs; rank-stable)
//   [336,592) edge bitmask atomicOr (edgebits pre-zeroed by memset)
// ---------------------------------------------------------------------------
__global__ __launch_bounds__(256) void k_front(
    const void* __restrict__ xraw, const int* __restrict__ ei,
    const void* __restrict__ g1w, const void* __restrict__ g1b,
    const void* __restrict__ g2w, const void* __restrict__ g2b,
    const void* __restrict__ qw, const void* __restrict__ kw,
    const void* __restrict__ vw, const void* __restrict__ ow,
    unsigned short* __restrict__ Xbf,
    unsigned short* __restrict__ qwB, unsigned short* __restrict__ kwB,
    unsigned short* __restrict__ vwB, unsigned short* __restrict__ owB,
    float* __restrict__ topo, unsigned* __restrict__ edgebits)
{
    int blk = blockIdx.x;
    int t = threadIdx.x;
    int fp = derive_fp32(xraw);

    if (blk < 64) {                                  // x -> bf16
        const int NV = (BB * NN * DD) / 4;
        for (int i = blk * 256 + t; i < NV; i += 64 * 256) {
            ushort4 o;
            if (fp) {
                float4 v = ((const float4*)xraw)[i];
                o.x = f2bf(v.x); o.y = f2bf(v.y); o.z = f2bf(v.z); o.w = f2bf(v.w);
            } else o = ((const ushort4*)xraw)[i];
            ((ushort4*)Xbf)[i] = o;
        }
    } else if (blk < 80) {                           // weights -> bf16
        int p = blk - 64;
        int tsr = p >> 2, sub = p & 3;
        const void* src = (tsr == 0) ? qw : (tsr == 1) ? kw : (tsr == 2) ? vw : ow;
        unsigned short* dst = (tsr == 0) ? qwB : (tsr == 1) ? kwB : (tsr == 2) ? vwB : owB;
        const int NV = (DD * DD) / 4;                // 16384
        for (int i = sub * 256 + t; i < NV; i += 4 * 256) {
            ushort4 o;
            if (fp) {
                float4 v = ((const float4*)src)[i];
                o.x = f2bf(v.x); o.y = f2bf(v.y); o.z = f2bf(v.z); o.w = f2bf(v.w);
            } else o = ((const ushort4*)src)[i];
            ((ushort4*)dst)[i] = o;
        }
    } else if (blk < 336) {                          // topo MLP
        __shared__ float xs[16][DD];
        __shared__ float wt[16][129];
        __shared__ float red[16][132];
        int c  = t & 127;
        int rg = t >> 7;
        int row0 = (blk - 80) * 16;

        if (fp) {
            const float4* X4 = (const float4*)xraw + (size_t)row0 * 64;
            for (int i = t; i < 16 * 64; i += 256) {
                int r = i >> 6, k4 = i & 63;
                *reinterpret_cast<float4*>(&xs[r][k4 * 4]) = X4[(size_t)r * 64 + k4];
            }
        } else {
            const ushort4* X4 = (const ushort4*)xraw + (size_t)row0 * 64;
            for (int i = t; i < 16 * 64; i += 256) {
                int r = i >> 6, k4 = i & 63;
                ushort4 u = X4[(size_t)r * 64 + k4];
                xs[r][k4 * 4 + 0] = bf2f(u.x);
                xs[r][k4 * 4 + 1] = bf2f(u.y);
                xs[r][k4 * 4 + 2] = bf2f(u.z);
                xs[r][k4 * 4 + 3] = bf2f(u.w);
            }
        }
        float acc[8];
#pragma unroll
        for (int r = 0; r < 8; ++r) acc[r] = 0.f;

        for (int kt = 0; kt < DD; kt += 16) {
            __syncthreads();
            for (int i = t; i < 128 * 16; i += 256) {
                int nn = i >> 4, kk = i & 15;
                wt[kk][nn] = loadf(g1w, nn * DD + kt + kk, fp);
            }
            __syncthreads();
            float wv[16];
#pragma unroll
            for (int kk = 0; kk < 16; ++kk) wv[kk] = wt[kk][c];
#pragma unroll
            for (int r = 0; r < 8; ++r) {
                const float* xr = &xs[rg * 8 + r][kt];
                float4 x0 = *reinterpret_cast<const float4*>(xr);
                float4 x1 = *reinterpret_cast<const float4*>(xr + 4);
                float4 x2 = *reinterpret_cast<const float4*>(xr + 8);
                float4 x3 = *reinterpret_cast<const float4*>(xr + 12);
                acc[r] += x0.x*wv[0] + x0.y*wv[1] + x0.z*wv[2] + x0.w*wv[3]
                        + x1.x*wv[4] + x1.y*wv[5] + x1.z*wv[6] + x1.w*wv[7]
                        + x2.x*wv[8] + x2.y*wv[9] + x2.z*wv[10] + x2.w*wv[11]
                        + x3.x*wv[12] + x3.y*wv[13] + x3.z*wv[14] + x3.w*wv[15];
            }
        }
        float gb = loadf(g1b, c, fp), gw = loadf(g2w, c, fp);
#pragma unroll
        for (int r = 0; r < 8; ++r)
            red[rg * 8 + r][c] = fmaxf(acc[r] + gb, 0.f) * gw;
        __syncthreads();
        int rr = t >> 4, ii = t & 15;
        float p = 0.f;
#pragma unroll
        for (int j = 0; j < 8; ++j) p += red[rr][ii * 8 + j];
#pragma unroll
        for (int o = 1; o < 16; o <<= 1) p += __shfl_xor(p, o, 64);
        if (ii == 0) topo[row0 + rr] = p + loadf(g2b, 0, fp);
    } else {                                         // edge bitmask
        int e = (blk - 336) * 256 + t;
        if (e < EE) {
            int r = ei[e];
            int c = ei[EE + e];
            atomicOr(&edgebits[r * 64 + (c >> 5)], 1u << (c & 31));
        }
    }
}

// ---------------------------------------------------------------------------
// MID layer (one dispatch): blocks
//   [0,16)   stable top-k rank -> colbits
//   [16,272) fused Q/K/V MFMA projection
// ---------------------------------------------------------------------------
__global__ __launch_bounds__(256) void k_mid(
    const void* __restrict__ xraw,
    const float* __restrict__ topo, unsigned* __restrict__ colbits,
    const unsigned short* __restrict__ Xb,
    const unsigned short* __restrict__ Wq, const unsigned short* __restrict__ Wk,
    const unsigned short* __restrict__ Wv,
    const void* __restrict__ bq, const void* __restrict__ bk, const void* __restrict__ bv,
    unsigned short* __restrict__ Qo, unsigned short* __restrict__ Ko,
    unsigned short* __restrict__ Vo, float qscale)
{
    int blk = blockIdx.x;
    int t = threadIdx.x;

    if (blk < 16) {                                  // rank
        __shared__ float tl[NN];
        int b = blk >> 3;
        int m = (blk & 7) * 256 + t;
        for (int i = t; i < NN / 4; i += 256)
            *reinterpret_cast<float4*>(&tl[i * 4]) =
                reinterpret_cast<const float4*>(topo + b * NN)[i];
        __syncthreads();
        float v = tl[m];
        int rank = 0;
        for (int j4 = 0; j4 < NN / 4; ++j4) {
            float4 q = *reinterpret_cast<const float4*>(&tl[j4 * 4]);
            int j = j4 * 4;
            rank += (q.x > v) || (q.x == v && (j + 0) < m);
            rank += (q.y > v) || (q.y == v && (j + 1) < m);
            rank += (q.z > v) || (q.z == v && (j + 2) < m);
            rank += (q.w > v) || (q.w == v && (j + 3) < m);
        }
        if (rank < KTOP) atomicOr(&colbits[b * 64 + (m >> 5)], 1u << (m & 31));
        return;
    }

    // QKV projection
    int fp = derive_fp32(xraw);
    int p = blk - 16;
    int bx = p & 63, by = p >> 6;
    int w = t >> 6, lane = t & 63, q4 = lane >> 4, l16 = lane & 15;
    int m0 = bx * 64 + w * 16;
    int nb = by * 64;

    f32x4 aq[4] = {}, ak[4] = {}, av[4] = {};
#pragma unroll
    for (int ks = 0; ks < 8; ++ks) {
        bf16x8 a = *reinterpret_cast<const bf16x8*>(Xb + (size_t)(m0 + l16) * DD + ks * 32 + q4 * 8);
#pragma unroll
        for (int n = 0; n < 4; ++n) {
            size_t wo = (size_t)(nb + n * 16 + l16) * DD + ks * 32 + q4 * 8;
            bf16x8 b0 = *reinterpret_cast<const bf16x8*>(Wq + wo);
            bf16x8 b1 = *reinterpret_cast<const bf16x8*>(Wk + wo);
            bf16x8 b2 = *reinterpret_cast<const bf16x8*>(Wv + wo);
            aq[n] = __builtin_amdgcn_mfma_f32_16x16x32_bf16(a, b0, aq[n], 0, 0, 0);
            ak[n] = __builtin_amdgcn_mfma_f32_16x16x32_bf16(a, b1, ak[n], 0, 0, 0);
            av[n] = __builtin_amdgcn_mfma_f32_16x16x32_bf16(a, b2, av[n], 0, 0, 0);
        }
    }
#pragma unroll
    for (int n = 0; n < 4; ++n) {
        int col = nb + n * 16 + l16;
        int h = col >> 5, j = col & (HD - 1);
        float bvq = loadf(bq, col, fp), bvk = loadf(bk, col, fp), bvv = loadf(bv, col, fp);
#pragma unroll
        for (int i = 0; i < 4; ++i) {
            int row = m0 + q4 * 4 + i;
            int b = row >> 11, n2 = row & (NN - 1);
            size_t ho = (((size_t)(b * HH + h)) * NN + n2) * HD + j;
            Qo[ho] = f2bf((aq[n][i] + bvq) * qscale);
            Ko[ho] = f2bf(ak[n][i] + bvk);
            Vo[(((size_t)(b * HH + h)) * HD + j) * NN + n2] = f2bf(av[n][i] + bvv);
        }
    }
}

// ---------------------------------------------------------------------------
// ATTN + MASKOUT layer (one dispatch): blocks
//   [0,1024)       masked attention, MFMA, split-K (NSPLIT=2), prefetch rot.
//   [1024,1024+4096) sparse_mask writer (dtype per inline flag)
// ---------------------------------------------------------------------------
__global__ __launch_bounds__(256) void k_attnmask(
    const void* __restrict__ xraw,
    const unsigned short* __restrict__ Qbf, const unsigned short* __restrict__ Kbf,
    const unsigned short* __restrict__ Vt,
    const unsigned* __restrict__ edgebits, const unsigned* __restrict__ colbits,
    float* __restrict__ Opart, float* __restrict__ Zpart, float* __restrict__ Spart,
    void* __restrict__ dout)
{
    __shared__ unsigned mw[64][33];
    __shared__ short Pl[4][2][16 * 40];
    int blk = blockIdx.x;
    int t = threadIdx.x;

    if (blk >= 1024) {                               // maskout
        int row = blk - 1024;                        // b*N + n
        int b = row >> 11, n = row & (NN - 1);
        int fp = derive_fp32(xraw);
        unsigned wv = edgebits[n * 64 + (t >> 2)] | colbits[b * 64 + (t >> 2)];
        unsigned bits = (wv >> ((t & 3) * 8)) & 0xFFu;
        if (fp) {
            float v[8];
#pragma unroll
            for (int i = 0; i < 8; ++i) v[i] = ((bits >> i) & 1) ? 1.f : 0.f;
            float* base = (float*)dout + (size_t)BB * NN * DD;
#pragma unroll
            for (int h = 0; h < HH; ++h) {
                size_t idx = ((((size_t)(b * HH + h)) * NN + n) * NN) + (size_t)t * 8;
                *reinterpret_cast<float4*>(base + idx)     = make_float4(v[0], v[1], v[2], v[3]);
                *reinterpret_cast<float4*>(base + idx + 4) = make_float4(v[4], v[5], v[6], v[7]);
            }
        } else {
            unsigned v[8];
#pragma unroll
            for (int i = 0; i < 8; ++i) v[i] = ((bits >> i) & 1) ? 0x3F80u : 0u;
            uint4 o4;
            o4.x = v[0] | (v[1] << 16);
            o4.y = v[2] | (v[3] << 16);
            o4.z = v[4] | (v[5] << 16);
            o4.w = v[6] | (v[7] << 16);
            unsigned short* base = (unsigned short*)dout + (size_t)BB * NN * DD;
#pragma unroll
            for (int h = 0; h < HH; ++h) {
                size_t idx = ((((size_t)(b * HH + h)) * NN + n) * NN) + (size_t)t * 8;
                *reinterpret_cast<uint4*>(base + idx) = o4;
            }
        }
        return;
    }

    // attention
    int a = blk;
    int split = a & 1;
    int rt    = (a >> 1) & 31;
    int h     = (a >> 6) & 7;
    int b     = a >> 9;
    int w    = t >> 6;
    int lane = t & 63;
    int q4   = lane >> 4;
    int l16  = lane & 15;

    const int r0 = rt * 64;
    const int c0 = split * 32;
    for (int i = t; i < 64 * 32; i += 256) {
        int r = i >> 5, wd = i & 31;
        mw[r][wd] = edgebits[(r0 + r) * 64 + c0 + wd] | colbits[b * 64 + c0 + wd];
    }
    __syncthreads();

    const unsigned short* Qp = Qbf + ((size_t)(b * HH + h)) * NN * HD;
    const unsigned short* Kp = Kbf + ((size_t)(b * HH + h)) * NN * HD;
    const unsigned short* Vp = Vt  + ((size_t)(b * HH + h)) * HD * NN;

    bf16x8 afrag = *reinterpret_cast<const bf16x8*>(Qp + (size_t)(r0 + w * 16 + l16) * HD + q4 * 8);

    f32x4 O0 = {0.f, 0.f, 0.f, 0.f}, O1 = {0.f, 0.f, 0.f, 0.f};
    float Zp[4] = {0.f, 0.f, 0.f, 0.f}, Sp[4] = {0.f, 0.f, 0.f, 0.f};

    bf16x8 kb0, kb1, vb0, vb1;
    {
        int n0 = c0 * 32;
        kb0 = *reinterpret_cast<const bf16x8*>(Kp + (size_t)(n0 + 2 * l16) * HD + q4 * 8);
        kb1 = *reinterpret_cast<const bf16x8*>(Kp + (size_t)(n0 + 2 * l16 + 1) * HD + q4 * 8);
        vb0 = *reinterpret_cast<const bf16x8*>(Vp + (size_t)l16 * NN + n0 + q4 * 8);
        vb1 = *reinterpret_cast<const bf16x8*>(Vp + (size_t)(16 + l16) * NN + n0 + q4 * 8);
    }

    for (int chl = 0; chl < 32; ++chl) {
        int nxt = (chl + 1 < 32) ? chl + 1 : 31;
        int nn0 = (c0 + nxt) * 32;
        bf16x8 nk0 = *reinterpret_cast<const bf16x8*>(Kp + (size_t)(nn0 + 2 * l16) * HD + q4 * 8);
        bf16x8 nk1 = *reinterpret_cast<const bf16x8*>(Kp + (size_t)(nn0 + 2 * l16 + 1) * HD + q4 * 8);
        bf16x8 nv0 = *reinterpret_cast<const bf16x8*>(Vp + (size_t)l16 * NN + nn0 + q4 * 8);
        bf16x8 nv1 = *reinterpret_cast<const bf16x8*>(Vp + (size_t)(16 + l16) * NN + nn0 + q4 * 8);

        f32x4 s0 = __builtin_amdgcn_mfma_f32_16x16x32_bf16(afrag, kb0, (f32x4){0.f,0.f,0.f,0.f}, 0, 0, 0);
        f32x4 s1 = __builtin_amdgcn_mfma_f32_16x16x32_bf16(afrag, kb1, (f32x4){0.f,0.f,0.f,0.f}, 0, 0, 0);

        unsigned* P32 = reinterpret_cast<unsigned*>(&Pl[w][chl & 1][0]);
#pragma unroll
        for (int i = 0; i < 4; ++i) {
            int rl = w * 16 + q4 * 4 + i;
            unsigned wdv = mw[rl][chl];
            float e0 = __expf(s0[i]);
            float e1 = __expf(s1[i]);
            float m0 = ((wdv >> (2 * l16)) & 1u) ? e0 : 0.f;
            float m1 = ((wdv >> (2 * l16 + 1)) & 1u) ? e1 : 0.f;
            Zp[i] += e0 + e1;
            Sp[i] += m0 + m1;
            P32[(q4 * 4 + i) * 20 + l16] =
                (__float_as_uint(m0) >> 16) | (__float_as_uint(m1) & 0xFFFF0000u);
        }
        bf16x8 pfrag = *reinterpret_cast<const bf16x8*>(&Pl[w][chl & 1][l16 * 40 + q4 * 8]);
        O0 = __builtin_amdgcn_mfma_f32_16x16x32_bf16(pfrag, vb0, O0, 0, 0, 0);
        O1 = __builtin_amdgcn_mfma_f32_16x16x32_bf16(pfrag, vb1, O1, 0, 0, 0);

        kb0 = nk0; kb1 = nk1; vb0 = nv0; vb1 = nv1;
    }

#pragma unroll
    for (int o = 1; o < 16; o <<= 1) {
#pragma unroll
        for (int i = 0; i < 4; ++i) {
            Zp[i] += __shfl_xor(Zp[i], o, 64);
            Sp[i] += __shfl_xor(Sp[i], o, 64);
        }
    }
#pragma unroll
    for (int i = 0; i < 4; ++i) {
        int n = r0 + w * 16 + q4 * 4 + i;
        float* op = Opart + (size_t)split * BB * NN * DD + ((size_t)(b * NN + n)) * DD + h * HD;
        op[l16]      = O0[i];
        op[16 + l16] = O1[i];
        if (l16 == 0) {
            size_t zi = (((size_t)(split * BB + b)) * HH + h) * NN + n;
            Zpart[zi] = Zp[i];
            Spart[zi] = Sp[i];
        }
    }
}

// ---------------------------------------------------------------------------
// O-projection GEMM (MFMA) with fused split-K combine + normalize.
// ---------------------------------------------------------------------------
__global__ __launch_bounds__(256) void k_projO(
    const void* __restrict__ xraw,
    const float* __restrict__ Opart, const float* __restrict__ Zpart,
    const float* __restrict__ Spart,
    const unsigned short* __restrict__ Wb, const void* __restrict__ bias,
    void* __restrict__ dout)
{
    int t = threadIdx.x;
    int fp = derive_fp32(xraw);
    int w = t >> 6, lane = t & 63, q4 = lane >> 4, l16 = lane & 15;
    int m0 = blockIdx.x * 64 + w * 16;
    int nb = blockIdx.y * 64;
    int arow = m0 + l16;
    int ab = arow >> 11, an = arow & (NN - 1);

    f32x4 acc[4] = {};
#pragma unroll
    for (int ks = 0; ks < 8; ++ks) {        // head h = ks
        size_t zi0 = (((size_t)(0 * BB + ab)) * HH + ks) * NN + an;
        size_t zi1 = (((size_t)(1 * BB + ab)) * HH + ks) * NN + an;
        float Zt = Zpart[zi0] + Zpart[zi1];
        float St = Spart[zi0] + Spart[zi1];
        float inv = 1.f / (St + 1e-8f * Zt);
        const float* o0 = Opart + (size_t)arow * DD + ks * 32 + q4 * 8;
        const float* o1 = o0 + (size_t)BB * NN * DD;
        bf16x8 a;
#pragma unroll
        for (int j = 0; j < 8; ++j)
            a[j] = (short)f2bf((o0[j] + o1[j]) * inv);
#pragma unroll
        for (int n = 0; n < 4; ++n) {
            bf16x8 bf = *reinterpret_cast<const bf16x8*>(Wb + (size_t)(nb + n * 16 + l16) * DD + ks * 32 + q4 * 8);
            acc[n] = __builtin_amdgcn_mfma_f32_16x16x32_bf16(a, bf, acc[n], 0, 0, 0);
        }
    }
#pragma unroll
    for (int n = 0; n < 4; ++n) {
        int col = nb + n * 16 + l16;
        float bv = loadf(bias, col, fp);
#pragma unroll
        for (int i = 0; i < 4; ++i) {
            int row = m0 + q4 * 4 + i;
            float v = acc[n][i] + bv;
            if (fp) ((float*)dout)[(size_t)row * DD + col] = v;
            else ((unsigned short*)dout)[(size_t)row * DD + col] = f2bf(v);
        }
    }
}

// ---------------------------------------------------------------------------
extern "C" void kernel_launch(void* const* d_in, const int* in_sizes, int n_in,
                              void* d_out, int out_size, void* d_ws, size_t ws_size,
                              hipStream_t stream)
{
    const void* x   = d_in[0];
    const int*  ei  = (const int*)d_in[1];

    // workspace layout (bytes)
    char* ws = (char*)d_ws;
    constexpr size_t OFF_EB   = 0;
    constexpr size_t OFF_CB   = OFF_EB  + (size_t)NN * 64 * 4;        // 524288
    constexpr size_t OFF_TOPO = OFF_CB  + (size_t)BB * 64 * 4;        // 524800
    constexpr size_t OFF_Q    = OFF_TOPO + (size_t)BB * NN * 4;       // 541184
    constexpr size_t OFF_K    = OFF_Q   + (size_t)BB * NN * DD * 2;
    constexpr size_t OFF_VT   = OFF_K   + (size_t)BB * NN * DD * 2;
    constexpr size_t OFF_XB   = OFF_VT  + (size_t)BB * NN * DD * 2;
    constexpr size_t OFF_QWB  = OFF_XB  + (size_t)BB * NN * DD * 2;
    constexpr size_t OFF_KWB  = OFF_QWB + (size_t)DD * DD * 2;
    constexpr size_t OFF_VWB  = OFF_KWB + (size_t)DD * DD * 2;
    constexpr size_t OFF_OWB  = OFF_VWB + (size_t)DD * DD * 2;
    constexpr size_t OFF_OP   = OFF_OWB + (size_t)DD * DD * 2;
    constexpr size_t OFF_ZP   = OFF_OP  + (size_t)NSPLIT * BB * NN * DD * 4;
    constexpr size_t OFF_SP   = OFF_ZP  + (size_t)NSPLIT * BB * HH * NN * 4;

    unsigned* edgebits = (unsigned*)(ws + OFF_EB);
    unsigned* colbits  = (unsigned*)(ws + OFF_CB);
    float*    topo     = (float*)(ws + OFF_TOPO);
    unsigned short* Qbf = (unsigned short*)(ws + OFF_Q);
    unsigned short* Kbf = (unsigned short*)(ws + OFF_K);
    unsigned short* Vtb = (unsigned short*)(ws + OFF_VT);
    unsigned short* Xbf = (unsigned short*)(ws + OFF_XB);
    unsigned short* qwB = (unsigned short*)(ws + OFF_QWB);
    unsigned short* kwB = (unsigned short*)(ws + OFF_KWB);
    unsigned short* vwB = (unsigned short*)(ws + OFF_VWB);
    unsigned short* owB = (unsigned short*)(ws + OFF_OWB);
    float*    Opart    = (float*)(ws + OFF_OP);
    float*    Zpart    = (float*)(ws + OFF_ZP);
    float*    Spart    = (float*)(ws + OFF_SP);

    // zero edge + col bitmasks
    hipMemsetAsync(d_ws, 0, OFF_TOPO, stream);

    k_front<<<dim3(592), dim3(256), 0, stream>>>(
        x, ei, d_in[10], d_in[11], d_in[12], d_in[13],
        d_in[2], d_in[4], d_in[6], d_in[8],
        Xbf, qwB, kwB, vwB, owB, topo, edgebits);

    const float qscale = 0.17677669529663687f;   // 1/sqrt(32)
    k_mid<<<dim3(272), dim3(256), 0, stream>>>(
        x, topo, colbits, Xbf, qwB, kwB, vwB,
        d_in[3], d_in[5], d_in[7], Qbf, Kbf, Vtb, qscale);

    k_attnmask<<<dim3(1024 + BB * NN), dim3(256), 0, stream>>>(
        x, Qbf, Kbf, Vtb, edgebits, colbits, Opart, Zpart, Spart, d_out);

    k_projO<<<dim3(BB * NN / 64, DD / 64), dim3(256), 0, stream>>>(
        x, Opart, Zpart, Spart, owB, d_in[9], d_out);
}

// Round 9
// 447.568 us; speedup vs baseline: 1.2956x; 1.0757x over previous
//
#include <hip/hip_runtime.h>
#include <hip/hip_bf16.h>

// Problem constants (B,N,D,H,E from reference; hd = D/H)
#define BB   2
#define NN   2048
#define DD   256
#define HH   8
#define HD   32
#define EE   65536
#define KTOP 1024   // N * (1 - 0.5)

typedef __attribute__((ext_vector_type(8))) short bf16x8;
typedef __attribute__((ext_vector_type(4))) float f32x4;

__device__ __forceinline__ float bf2f(unsigned short u) {
    return __uint_as_float(((unsigned)u) << 16);
}
__device__ __forceinline__ unsigned short f2bf(float f) {
    __hip_bfloat16 h = __float2bfloat16(f);
    return *reinterpret_cast<unsigned short*>(&h);
}
// raw scalar load with dtype branch
__device__ __forceinline__ float loadf(const void* p, int i, int fp) {
    return fp ? ((const float*)p)[i] : bf2f(((const unsigned short*)p)[i]);
}

// ---------------------------------------------------------------------------
// Inline dtype detection: wave ballot over first 64 u32 words of x.
// fp32 misread as bf16 -> low halves have random exponents -> |v| > 1e10
// w.p. ~0.37 per word; P(miss over 64 words) ~ 1e-13. 1 = fp32, 0 = bf16.
// ---------------------------------------------------------------------------
__device__ __forceinline__ int derive_fp32(const void* x) {
    unsigned wv = ((const unsigned*)x)[threadIdx.x & 63];
    float a = fabsf(bf2f((unsigned short)(wv & 0xFFFFu)));
    float b = fabsf(bf2f((unsigned short)(wv >> 16)));
    bool bad = !(a <= 1e10f && b <= 1e10f);     // catches NaN/inf/huge
    return __ballot(bad) != 0ULL;
}

// ---------------------------------------------------------------------------
// FRONT layer (one dispatch): blocks
//   [0,64)    x -> Xbf (bf16)
//   [64,80)   qw/kw/vw/ow -> bf16
//   [80,336)  topo MLP (fp32 math from raw inputs; rank-stable)
//   [336,592) edge bitmask atomicOr (edgebits pre-zeroed by memset)
// ---------------------------------------------------------------------------
__global__ __launch_bounds__(256) void k_front(
    const void* __restrict__ xraw, const int* __restrict__ ei,
    const void* __restrict__ g1w, const void* __restrict__ g1b,
    const void* __restrict__ g2w, const void* __restrict__ g2b,
    const void* __restrict__ qw, const void* __restrict__ kw,
    const void* __restrict__ vw, const void* __restrict__ ow,
    unsigned short* __restrict__ Xbf,
    unsigned short* __restrict__ qwB, unsigned short* __restrict__ kwB,
    unsigned short* __restrict__ vwB, unsigned short* __restrict__ owB,
    float* __restrict__ topo, unsigned* __restrict__ edgebits)
{
    int blk = blockIdx.x;
    int t = threadIdx.x;
    int fp = derive_fp32(xraw);

    if (blk < 64) {                                  // x -> bf16
        const int NV = (BB * NN * DD) / 4;
        for (int i = blk * 256 + t; i < NV; i += 64 * 256) {
            ushort4 o;
            if (fp) {
                float4 v = ((const float4*)xraw)[i];
                o.x = f2bf(v.x); o.y = f2bf(v.y); o.z = f2bf(v.z); o.w = f2bf(v.w);
            } else o = ((const ushort4*)xraw)[i];
            ((ushort4*)Xbf)[i] = o;
        }
    } else if (blk < 80) {                           // weights -> bf16
        int p = blk - 64;
        int tsr = p >> 2, sub = p & 3;
        const void* src = (tsr == 0) ? qw : (tsr == 1) ? kw : (tsr == 2) ? vw : ow;
        unsigned short* dst = (tsr == 0) ? qwB : (tsr == 1) ? kwB : (tsr == 2) ? vwB : owB;
        const int NV = (DD * DD) / 4;                // 16384
        for (int i = sub * 256 + t; i < NV; i += 4 * 256) {
            ushort4 o;
            if (fp) {
                float4 v = ((const float4*)src)[i];
                o.x = f2bf(v.x); o.y = f2bf(v.y); o.z = f2bf(v.z); o.w = f2bf(v.w);
            } else o = ((const ushort4*)src)[i];
            ((ushort4*)dst)[i] = o;
        }
    } else if (blk < 336) {                          // topo MLP
        __shared__ float xs[16][DD];
        __shared__ float wt[16][129];
        __shared__ float red[16][132];
        int c  = t & 127;
        int rg = t >> 7;
        int row0 = (blk - 80) * 16;

        if (fp) {
            const float4* X4 = (const float4*)xraw + (size_t)row0 * 64;
            for (int i = t; i < 16 * 64; i += 256) {
                int r = i >> 6, k4 = i & 63;
                *reinterpret_cast<float4*>(&xs[r][k4 * 4]) = X4[(size_t)r * 64 + k4];
            }
        } else {
            const ushort4* X4 = (const ushort4*)xraw + (size_t)row0 * 64;
            for (int i = t; i < 16 * 64; i += 256) {
                int r = i >> 6, k4 = i & 63;
                ushort4 u = X4[(size_t)r * 64 + k4];
                xs[r][k4 * 4 + 0] = bf2f(u.x);
                xs[r][k4 * 4 + 1] = bf2f(u.y);
                xs[r][k4 * 4 + 2] = bf2f(u.z);
                xs[r][k4 * 4 + 3] = bf2f(u.w);
            }
        }
        float acc[8];
#pragma unroll
        for (int r = 0; r < 8; ++r) acc[r] = 0.f;

        for (int kt = 0; kt < DD; kt += 16) {
            __syncthreads();
            for (int i = t; i < 128 * 16; i += 256) {
                int nn = i >> 4, kk = i & 15;
                wt[kk][nn] = loadf(g1w, nn * DD + kt + kk, fp);
            }
            __syncthreads();
            float wv[16];
#pragma unroll
            for (int kk = 0; kk < 16; ++kk) wv[kk] = wt[kk][c];
#pragma unroll
            for (int r = 0; r < 8; ++r) {
                const float* xr = &xs[rg * 8 + r][kt];
                float4 x0 = *reinterpret_cast<const float4*>(xr);
                float4 x1 = *reinterpret_cast<const float4*>(xr + 4);
                float4 x2 = *reinterpret_cast<const float4*>(xr + 8);
                float4 x3 = *reinterpret_cast<const float4*>(xr + 12);
                acc[r] += x0.x*wv[0] + x0.y*wv[1] + x0.z*wv[2] + x0.w*wv[3]
                        + x1.x*wv[4] + x1.y*wv[5] + x1.z*wv[6] + x1.w*wv[7]
                        + x2.x*wv[8] + x2.y*wv[9] + x2.z*wv[10] + x2.w*wv[11]
                        + x3.x*wv[12] + x3.y*wv[13] + x3.z*wv[14] + x3.w*wv[15];
            }
        }
        float gb = loadf(g1b, c, fp), gw = loadf(g2w, c, fp);
#pragma unroll
        for (int r = 0; r < 8; ++r)
            red[rg * 8 + r][c] = fmaxf(acc[r] + gb, 0.f) * gw;
        __syncthreads();
        int rr = t >> 4, ii = t & 15;
        float p = 0.f;
#pragma unroll
        for (int j = 0; j < 8; ++j) p += red[rr][ii * 8 + j];
#pragma unroll
        for (int o = 1; o < 16; o <<= 1) p += __shfl_xor(p, o, 64);
        if (ii == 0) topo[row0 + rr] = p + loadf(g2b, 0, fp);
    } else {                                         // edge bitmask
        int e = (blk - 336) * 256 + t;
        if (e < EE) {
            int r = ei[e];
            int c = ei[EE + e];
            atomicOr(&edgebits[r * 64 + (c >> 5)], 1u << (c & 31));
        }
    }
}

// ---------------------------------------------------------------------------
// MID layer (one dispatch): blocks
//   [0,16)   stable top-k rank -> colbits
//   [16,272) fused Q/K/V MFMA projection
// ---------------------------------------------------------------------------
__global__ __launch_bounds__(256) void k_mid(
    const void* __restrict__ xraw,
    const float* __restrict__ topo, unsigned* __restrict__ colbits,
    const unsigned short* __restrict__ Xb,
    const unsigned short* __restrict__ Wq, const unsigned short* __restrict__ Wk,
    const unsigned short* __restrict__ Wv,
    const void* __restrict__ bq, const void* __restrict__ bk, const void* __restrict__ bv,
    unsigned short* __restrict__ Qo, unsigned short* __restrict__ Ko,
    unsigned short* __restrict__ Vo, float qscale)
{
    int blk = blockIdx.x;
    int t = threadIdx.x;

    if (blk < 16) {                                  // rank
        __shared__ float tl[NN];
        int b = blk >> 3;
        int m = (blk & 7) * 256 + t;
        for (int i = t; i < NN / 4; i += 256)
            *reinterpret_cast<float4*>(&tl[i * 4]) =
                reinterpret_cast<const float4*>(topo + b * NN)[i];
        __syncthreads();
        float v = tl[m];
        int rank = 0;
        for (int j4 = 0; j4 < NN / 4; ++j4) {
            float4 q = *reinterpret_cast<const float4*>(&tl[j4 * 4]);
            int j = j4 * 4;
            rank += (q.x > v) || (q.x == v && (j + 0) < m);
            rank += (q.y > v) || (q.y == v && (j + 1) < m);
            rank += (q.z > v) || (q.z == v && (j + 2) < m);
            rank += (q.w > v) || (q.w == v && (j + 3) < m);
        }
        if (rank < KTOP) atomicOr(&colbits[b * 64 + (m >> 5)], 1u << (m & 31));
        return;
    }

    // QKV projection
    int fp = derive_fp32(xraw);
    int p = blk - 16;
    int bx = p & 63, by = p >> 6;
    int w = t >> 6, lane = t & 63, q4 = lane >> 4, l16 = lane & 15;
    int m0 = bx * 64 + w * 16;
    int nb = by * 64;

    f32x4 aq[4] = {}, ak[4] = {}, av[4] = {};
#pragma unroll
    for (int ks = 0; ks < 8; ++ks) {
        bf16x8 a = *reinterpret_cast<const bf16x8*>(Xb + (size_t)(m0 + l16) * DD + ks * 32 + q4 * 8);
#pragma unroll
        for (int n = 0; n < 4; ++n) {
            size_t wo = (size_t)(nb + n * 16 + l16) * DD + ks * 32 + q4 * 8;
            bf16x8 b0 = *reinterpret_cast<const bf16x8*>(Wq + wo);
            bf16x8 b1 = *reinterpret_cast<const bf16x8*>(Wk + wo);
            bf16x8 b2 = *reinterpret_cast<const bf16x8*>(Wv + wo);
            aq[n] = __builtin_amdgcn_mfma_f32_16x16x32_bf16(a, b0, aq[n], 0, 0, 0);
            ak[n] = __builtin_amdgcn_mfma_f32_16x16x32_bf16(a, b1, ak[n], 0, 0, 0);
            av[n] = __builtin_amdgcn_mfma_f32_16x16x32_bf16(a, b2, av[n], 0, 0, 0);
        }
    }
#pragma unroll
    for (int n = 0; n < 4; ++n) {
        int col = nb + n * 16 + l16;
        int h = col >> 5, j = col & (HD - 1);
        float bvq = loadf(bq, col, fp), bvk = loadf(bk, col, fp), bvv = loadf(bv, col, fp);
#pragma unroll
        for (int i = 0; i < 4; ++i) {
            int row = m0 + q4 * 4 + i;
            int b = row >> 11, n2 = row & (NN - 1);
            size_t ho = (((size_t)(b * HH + h)) * NN + n2) * HD + j;
            Qo[ho] = f2bf((aq[n][i] + bvq) * qscale);
            Ko[ho] = f2bf(ak[n][i] + bvk);
            Vo[(((size_t)(b * HH + h)) * HD + j) * NN + n2] = f2bf(av[n][i] + bvv);
        }
    }
}

// ---------------------------------------------------------------------------
// ATTN + MASKOUT layer (one dispatch): blocks
//   [0,512)        masked attention, MFMA, full-row (64 chunks), prefetch
//                  rotation, in-kernel normalize -> bf16 AO.
//   [512,512+4096) sparse_mask writer (dtype per inline flag)
// ---------------------------------------------------------------------------
__global__ __launch_bounds__(256) void k_attnmask(
    const void* __restrict__ xraw,
    const unsigned short* __restrict__ Qbf, const unsigned short* __restrict__ Kbf,
    const unsigned short* __restrict__ Vt,
    const unsigned* __restrict__ edgebits, const unsigned* __restrict__ colbits,
    unsigned short* __restrict__ AOb, void* __restrict__ dout)
{
    __shared__ unsigned mw[64][65];
    __shared__ short Pl[4][2][16 * 40];
    int blk = blockIdx.x;
    int t = threadIdx.x;

    if (blk >= 512) {                                // maskout
        int row = blk - 512;                         // b*N + n
        int b = row >> 11, n = row & (NN - 1);
        int fp = derive_fp32(xraw);
        unsigned wv = edgebits[n * 64 + (t >> 2)] | colbits[b * 64 + (t >> 2)];
        unsigned bits = (wv >> ((t & 3) * 8)) & 0xFFu;
        if (fp) {
            float v[8];
#pragma unroll
            for (int i = 0; i < 8; ++i) v[i] = ((bits >> i) & 1) ? 1.f : 0.f;
            float* base = (float*)dout + (size_t)BB * NN * DD;
#pragma unroll
            for (int h = 0; h < HH; ++h) {
                size_t idx = ((((size_t)(b * HH + h)) * NN + n) * NN) + (size_t)t * 8;
                *reinterpret_cast<float4*>(base + idx)     = make_float4(v[0], v[1], v[2], v[3]);
                *reinterpret_cast<float4*>(base + idx + 4) = make_float4(v[4], v[5], v[6], v[7]);
            }
        } else {
            unsigned v[8];
#pragma unroll
            for (int i = 0; i < 8; ++i) v[i] = ((bits >> i) & 1) ? 0x3F80u : 0u;
            uint4 o4;
            o4.x = v[0] | (v[1] << 16);
            o4.y = v[2] | (v[3] << 16);
            o4.z = v[4] | (v[5] << 16);
            o4.w = v[6] | (v[7] << 16);
            unsigned short* base = (unsigned short*)dout + (size_t)BB * NN * DD;
#pragma unroll
            for (int h = 0; h < HH; ++h) {
                size_t idx = ((((size_t)(b * HH + h)) * NN + n) * NN) + (size_t)t * 8;
                *reinterpret_cast<uint4*>(base + idx) = o4;
            }
        }
        return;
    }

    // attention: blk in [0,512): rt = blk&31, h = (blk>>5)&7, b = blk>>8
    int rt = blk & 31;
    int h  = (blk >> 5) & 7;
    int b  = blk >> 8;
    int w    = t >> 6;
    int lane = t & 63;
    int q4   = lane >> 4;
    int l16  = lane & 15;

    const int r0 = rt * 64;
    for (int i = t; i < 64 * 64; i += 256) {
        int r = i >> 6, wd = i & 63;
        mw[r][wd] = edgebits[(r0 + r) * 64 + wd] | colbits[b * 64 + wd];
    }
    __syncthreads();

    const unsigned short* Qp = Qbf + ((size_t)(b * HH + h)) * NN * HD;
    const unsigned short* Kp = Kbf + ((size_t)(b * HH + h)) * NN * HD;
    const unsigned short* Vp = Vt  + ((size_t)(b * HH + h)) * HD * NN;

    bf16x8 afrag = *reinterpret_cast<const bf16x8*>(Qp + (size_t)(r0 + w * 16 + l16) * HD + q4 * 8);

    f32x4 O0 = {0.f, 0.f, 0.f, 0.f}, O1 = {0.f, 0.f, 0.f, 0.f};
    float Zp[4] = {0.f, 0.f, 0.f, 0.f}, Sp[4] = {0.f, 0.f, 0.f, 0.f};

    bf16x8 kb0, kb1, vb0, vb1;
    {
        kb0 = *reinterpret_cast<const bf16x8*>(Kp + (size_t)(2 * l16) * HD + q4 * 8);
        kb1 = *reinterpret_cast<const bf16x8*>(Kp + (size_t)(2 * l16 + 1) * HD + q4 * 8);
        vb0 = *reinterpret_cast<const bf16x8*>(Vp + (size_t)l16 * NN + q4 * 8);
        vb1 = *reinterpret_cast<const bf16x8*>(Vp + (size_t)(16 + l16) * NN + q4 * 8);
    }

    for (int chl = 0; chl < 64; ++chl) {
        int nxt = (chl + 1 < 64) ? chl + 1 : 63;
        int nn0 = nxt * 32;
        bf16x8 nk0 = *reinterpret_cast<const bf16x8*>(Kp + (size_t)(nn0 + 2 * l16) * HD + q4 * 8);
        bf16x8 nk1 = *reinterpret_cast<const bf16x8*>(Kp + (size_t)(nn0 + 2 * l16 + 1) * HD + q4 * 8);
        bf16x8 nv0 = *reinterpret_cast<const bf16x8*>(Vp + (size_t)l16 * NN + nn0 + q4 * 8);
        bf16x8 nv1 = *reinterpret_cast<const bf16x8*>(Vp + (size_t)(16 + l16) * NN + nn0 + q4 * 8);

        f32x4 s0 = __builtin_amdgcn_mfma_f32_16x16x32_bf16(afrag, kb0, (f32x4){0.f,0.f,0.f,0.f}, 0, 0, 0);
        f32x4 s1 = __builtin_amdgcn_mfma_f32_16x16x32_bf16(afrag, kb1, (f32x4){0.f,0.f,0.f,0.f}, 0, 0, 0);

        unsigned* P32 = reinterpret_cast<unsigned*>(&Pl[w][chl & 1][0]);
#pragma unroll
        for (int i = 0; i < 4; ++i) {
            int rl = w * 16 + q4 * 4 + i;
            unsigned wdv = mw[rl][chl];
            float e0 = __expf(s0[i]);
            float e1 = __expf(s1[i]);
            float m0 = ((wdv >> (2 * l16)) & 1u) ? e0 : 0.f;
            float m1 = ((wdv >> (2 * l16 + 1)) & 1u) ? e1 : 0.f;
            Zp[i] += e0 + e1;
            Sp[i] += m0 + m1;
            P32[(q4 * 4 + i) * 20 + l16] =
                (__float_as_uint(m0) >> 16) | (__float_as_uint(m1) & 0xFFFF0000u);
        }
        bf16x8 pfrag = *reinterpret_cast<const bf16x8*>(&Pl[w][chl & 1][l16 * 40 + q4 * 8]);
        O0 = __builtin_amdgcn_mfma_f32_16x16x32_bf16(pfrag, vb0, O0, 0, 0, 0);
        O1 = __builtin_amdgcn_mfma_f32_16x16x32_bf16(pfrag, vb1, O1, 0, 0, 0);

        kb0 = nk0; kb1 = nk1; vb0 = nv0; vb1 = nv1;
    }

#pragma unroll
    for (int o = 1; o < 16; o <<= 1) {
#pragma unroll
        for (int i = 0; i < 4; ++i) {
            Zp[i] += __shfl_xor(Zp[i], o, 64);
            Sp[i] += __shfl_xor(Sp[i], o, 64);
        }
    }
#pragma unroll
    for (int i = 0; i < 4; ++i) {
        float inv = 1.f / (Sp[i] + 1e-8f * Zp[i]);
        int n = r0 + w * 16 + q4 * 4 + i;
        unsigned short* op = AOb + ((size_t)(b * NN + n)) * DD + h * HD;
        op[l16]      = f2bf(O0[i] * inv);
        op[16 + l16] = f2bf(O1[i] * inv);
    }
}

// ---------------------------------------------------------------------------
// O-projection GEMM (MFMA): A = AO (bf16 row-major [4096][256]),
// B = ow (bf16), out row-major to d_out (dtype per inline flag).
// ---------------------------------------------------------------------------
__global__ __launch_bounds__(256) void k_projO(
    const void* __restrict__ xraw,
    const unsigned short* __restrict__ AOb,
    const unsigned short* __restrict__ Wb, const void* __restrict__ bias,
    void* __restrict__ dout)
{
    int t = threadIdx.x;
    int fp = derive_fp32(xraw);
    int w = t >> 6, lane = t & 63, q4 = lane >> 4, l16 = lane & 15;
    int m0 = blockIdx.x * 64 + w * 16;
    int nb = blockIdx.y * 64;

    f32x4 acc[4] = {};
#pragma unroll
    for (int ks = 0; ks < 8; ++ks) {
        bf16x8 a = *reinterpret_cast<const bf16x8*>(AOb + (size_t)(m0 + l16) * DD + ks * 32 + q4 * 8);
#pragma unroll
        for (int n = 0; n < 4; ++n) {
            bf16x8 bf = *reinterpret_cast<const bf16x8*>(Wb + (size_t)(nb + n * 16 + l16) * DD + ks * 32 + q4 * 8);
            acc[n] = __builtin_amdgcn_mfma_f32_16x16x32_bf16(a, bf, acc[n], 0, 0, 0);
        }
    }
#pragma unroll
    for (int n = 0; n < 4; ++n) {
        int col = nb + n * 16 + l16;
        float bv = loadf(bias, col, fp);
#pragma unroll
        for (int i = 0; i < 4; ++i) {
            int row = m0 + q4 * 4 + i;
            float v = acc[n][i] + bv;
            if (fp) ((float*)dout)[(size_t)row * DD + col] = v;
            else ((unsigned short*)dout)[(size_t)row * DD + col] = f2bf(v);
        }
    }
}

// ---------------------------------------------------------------------------
extern "C" void kernel_launch(void* const* d_in, const int* in_sizes, int n_in,
                              void* d_out, int out_size, void* d_ws, size_t ws_size,
                              hipStream_t stream)
{
    const void* x   = d_in[0];
    const int*  ei  = (const int*)d_in[1];

    // workspace layout (bytes)
    char* ws = (char*)d_ws;
    constexpr size_t OFF_EB   = 0;
    constexpr size_t OFF_CB   = OFF_EB  + (size_t)NN * 64 * 4;        // 524288
    constexpr size_t OFF_TOPO = OFF_CB  + (size_t)BB * 64 * 4;        // 524800
    constexpr size_t OFF_Q    = OFF_TOPO + (size_t)BB * NN * 4;       // 541184
    constexpr size_t OFF_K    = OFF_Q   + (size_t)BB * NN * DD * 2;
    constexpr size_t OFF_VT   = OFF_K   + (size_t)BB * NN * DD * 2;
    constexpr size_t OFF_XB   = OFF_VT  + (size_t)BB * NN * DD * 2;
    constexpr size_t OFF_AOB  = OFF_XB  + (size_t)BB * NN * DD * 2;
    constexpr size_t OFF_QWB  = OFF_AOB + (size_t)BB * NN * DD * 2;
    constexpr size_t OFF_KWB  = OFF_QWB + (size_t)DD * DD * 2;
    constexpr size_t OFF_VWB  = OFF_KWB + (size_t)DD * DD * 2;
    constexpr size_t OFF_OWB  = OFF_VWB + (size_t)DD * DD * 2;

    unsigned* edgebits = (unsigned*)(ws + OFF_EB);
    unsigned* colbits  = (unsigned*)(ws + OFF_CB);
    float*    topo     = (float*)(ws + OFF_TOPO);
    unsigned short* Qbf = (unsigned short*)(ws + OFF_Q);
    unsigned short* Kbf = (unsigned short*)(ws + OFF_K);
    unsigned short* Vtb = (unsigned short*)(ws + OFF_VT);
    unsigned short* Xbf = (unsigned short*)(ws + OFF_XB);
    unsigned short* AOb = (unsigned short*)(ws + OFF_AOB);
    unsigned short* qwB = (unsigned short*)(ws + OFF_QWB);
    unsigned short* kwB = (unsigned short*)(ws + OFF_KWB);
    unsigned short* vwB = (unsigned short*)(ws + OFF_VWB);
    unsigned short* owB = (unsigned short*)(ws + OFF_OWB);

    // zero edge + col bitmasks
    hipMemsetAsync(d_ws, 0, OFF_TOPO, stream);

    k_front<<<dim3(592), dim3(256), 0, stream>>>(
        x, ei, d_in[10], d_in[11], d_in[12], d_in[13],
        d_in[2], d_in[4], d_in[6], d_in[8],
        Xbf, qwB, kwB, vwB, owB, topo, edgebits);

    const float qscale = 0.17677669529663687f;   // 1/sqrt(32)
    k_mid<<<dim3(272), dim3(256), 0, stream>>>(
        x, topo, colbits, Xbf, qwB, kwB, vwB,
        d_in[3], d_in[5], d_in[7], Qbf, Kbf, Vtb, qscale);

    k_attnmask<<<dim3(512 + BB * NN), dim3(256), 0, stream>>>(
        x, Qbf, Kbf, Vtb, edgebits, colbits, AOb, d_out);

    k_projO<<<dim3(BB * NN / 64, DD / 64), dim3(256), 0, stream>>>(
        x, AOb, owB, d_in[9], d_out);
}